// Round 9
// baseline (1500.716 us; speedup 1.0000x reference)
//
#include <hip/hip_runtime.h>
#include <cstdint>
#include <cstddef>

// ---------------- problem constants ----------------
#define B_   16
#define L_   1022
#define E_   1280
#define D_   512
#define H_   8
#define FF_  2048
#define NL_  4
#define DH_  64
#define BL_  (B_*L_)      // 16352
#define EPS_ 1e-5f
#define QSC_ 0.18033688011112042f   // 0.125 * log2(e)

typedef unsigned short u16;
typedef unsigned int   u32;
typedef unsigned long long u64;
typedef float f32x4 __attribute__((ext_vector_type(4)));
typedef short s16x8 __attribute__((ext_vector_type(8)));
typedef u32 u32x4 __attribute__((ext_vector_type(4)));

__device__ __forceinline__ u16 f2bf(float f) {
    u32 u = __builtin_bit_cast(u32, f);
    u += 0x7fffu + ((u >> 16) & 1u);
    return (u16)(u >> 16);
}
__device__ __forceinline__ float bf2f(u16 u) {
    return __builtin_bit_cast(float, (u32)u << 16);
}
__device__ __forceinline__ u32 pack2bf(float a, float b) {
    return (u32)f2bf(a) | ((u32)f2bf(b) << 16);
}

// ======================================================================
// fp32 -> bf16 cast, 8 elems/thread
// ======================================================================
__global__ __launch_bounds__(256)
void cast_k(const float* __restrict__ src, u16* __restrict__ dst, int n8) {
    int t = blockIdx.x * 256 + threadIdx.x;
    if (t >= n8) return;
    const float* s = src + (size_t)t * 8;
    float4 a = *(const float4*)(s);
    float4 b = *(const float4*)(s + 4);
    s16x8 o;
    o[0] = (short)f2bf(a.x); o[1] = (short)f2bf(a.y);
    o[2] = (short)f2bf(a.z); o[3] = (short)f2bf(a.w);
    o[4] = (short)f2bf(b.x); o[5] = (short)f2bf(b.y);
    o[6] = (short)f2bf(b.z); o[7] = (short)f2bf(b.w);
    *(s16x8*)(dst + (size_t)t * 8) = o;
}

// in_w cast with wq rows (row%1536 < 512) pre-scaled by QSC_ (exp2-domain
// softmax: folds the 1/sqrt(DH) * log2(e) factor into the Q projection)
__global__ __launch_bounds__(256)
void castq_k(const float* __restrict__ src, u16* __restrict__ dst, int n8) {
    int t = blockIdx.x * 256 + threadIdx.x;
    if (t >= n8) return;
    int row = t >> 6;                  // 512 cols / 8 per chunk
    float sc = (row % 1536) < 512 ? QSC_ : 1.0f;
    const float* s = src + (size_t)t * 8;
    float4 a = *(const float4*)(s);
    float4 b = *(const float4*)(s + 4);
    s16x8 o;
    o[0] = (short)f2bf(a.x * sc); o[1] = (short)f2bf(a.y * sc);
    o[2] = (short)f2bf(a.z * sc); o[3] = (short)f2bf(a.w * sc);
    o[4] = (short)f2bf(b.x * sc); o[5] = (short)f2bf(b.y * sc);
    o[6] = (short)f2bf(b.z * sc); o[7] = (short)f2bf(b.w * sc);
    *(s16x8*)(dst + (size_t)t * 8) = o;
}

// scaled q/k bias for the fused QK GEMM: qbs[i][j] = in_b[i*1536+j] * (j<512?QSC:1)
__global__ __launch_bounds__(256)
void qbias_k(const float* __restrict__ ib, float* __restrict__ qbs) {
    int t = blockIdx.x * 256 + threadIdx.x;
    if (t >= NL_ * 1024) return;
    int i = t >> 10, j = t & 1023;
    float sc = j < 512 ? QSC_ : 1.0f;
    qbs[t] = ib[i * 1536 + j] * sc;
}

// h1_w left half [128, 0:512] (row stride 1024) -> packed bf16 [128,512]
__global__ __launch_bounds__(256)
void h1cast_k(const float* __restrict__ src, u16* __restrict__ dst) {
    int t = blockIdx.x * 256 + threadIdx.x;
    if (t >= 128 * 512 / 8) return;
    int row = t >> 6, c8 = (t & 63) << 3;
    const float* s = src + (size_t)row * 1024 + c8;
    float4 a = *(const float4*)(s);
    float4 b = *(const float4*)(s + 4);
    s16x8 o;
    o[0] = (short)f2bf(a.x); o[1] = (short)f2bf(a.y);
    o[2] = (short)f2bf(a.z); o[3] = (short)f2bf(a.w);
    o[4] = (short)f2bf(b.x); o[5] = (short)f2bf(b.y);
    o[6] = (short)f2bf(b.z); o[7] = (short)f2bf(b.w);
    *(s16x8*)(dst + (size_t)row * 512 + c8) = o;
}

// ======================================================================
// RoPE cos/sin tables
// ======================================================================
__global__ void tables_k(float* __restrict__ ct, float* __restrict__ st) {
    int idx = blockIdx.x * blockDim.x + threadIdx.x;
    if (idx >= L_ * DH_) return;
    int l = idx / DH_;
    int d = idx % DH_;
    int j = d & 31;
    float invf = powf(10000.0f, -(float)(2 * j) / (float)DH_);
    float ang = (float)l * invf;
    ct[idx] = cosf(ang);
    st[idx] = sinf(ang);
}

// ======================================================================
// bf16 MFMA GEMM (reg-staged, r5-proven): C = act(A @ W^T + bias)(+resid)
// 128x128 tile, BK=64, 256 threads (4 waves 2x2), 4x4 16x16 frags/wave.
// ======================================================================
template<bool RELU, bool RESID, bool OUTBF, bool ROWBIAS>
__global__ __launch_bounds__(256)
void mgemm_k(const u16* __restrict__ A, const u16* __restrict__ W,
             const float* __restrict__ bias, const float* __restrict__ resid,
             void* __restrict__ Cout, int M, int N, int K)
{
    constexpr int LDT = 72;               // padded LDS row stride (bf16)
    __shared__ u16 As[128 * LDT];
    __shared__ u16 Ws[128 * LDT];
    const int nt = N >> 7;
    const int bx = blockIdx.x % nt;
    const int by = blockIdx.x / nt;
    const int m0 = by << 7, n0 = bx << 7;
    const int tid = threadIdx.x;
    const int lane = tid & 63, wid = tid >> 6;
    const int wr = wid >> 1, wc = wid & 1;
    const int lr = lane & 15, lk = lane >> 4;

    f32x4 acc[4][4];
#pragma unroll
    for (int m = 0; m < 4; m++)
#pragma unroll
        for (int n = 0; n < 4; n++) acc[m][n] = (f32x4)0.0f;

    for (int k0 = 0; k0 < K; k0 += 64) {
        s16x8 va[4], vw[4];
#pragma unroll
        for (int u = 0; u < 4; u++) {
            int ch = tid + (u << 8);          // 16B chunk id, 0..1023
            int r = ch >> 3, c8 = (ch & 7) << 3;
            int ar = m0 + r; if (ar >= M) ar = M - 1;
            va[u] = *(const s16x8*)(A + (size_t)ar * K + k0 + c8);
            vw[u] = *(const s16x8*)(W + (size_t)(n0 + r) * K + k0 + c8);
        }
        __syncthreads();   // previous iteration's LDS reads complete
#pragma unroll
        for (int u = 0; u < 4; u++) {
            int ch = tid + (u << 8);
            int r = ch >> 3, c8 = (ch & 7) << 3;
            *(s16x8*)&As[r * LDT + c8] = va[u];
            *(s16x8*)&Ws[r * LDT + c8] = vw[u];
        }
        __syncthreads();   // tiles staged
#pragma unroll
        for (int kk = 0; kk < 2; kk++) {
            s16x8 af[4], bf[4];
#pragma unroll
            for (int m = 0; m < 4; m++)
                af[m] = *(const s16x8*)&As[(wr * 64 + m * 16 + lr) * LDT + kk * 32 + lk * 8];
#pragma unroll
            for (int n = 0; n < 4; n++)
                bf[n] = *(const s16x8*)&Ws[(wc * 64 + n * 16 + lr) * LDT + kk * 32 + lk * 8];
#pragma unroll
            for (int m = 0; m < 4; m++)
#pragma unroll
                for (int n = 0; n < 4; n++)
                    acc[m][n] = __builtin_amdgcn_mfma_f32_16x16x32_bf16(
                        af[m], bf[n], acc[m][n], 0, 0, 0);
        }
    }

    float bv[4];
    if constexpr (!ROWBIAS) {
#pragma unroll
        for (int n = 0; n < 4; n++) bv[n] = bias[n0 + wc * 64 + n * 16 + lr];
    }
#pragma unroll
    for (int m = 0; m < 4; m++) {
#pragma unroll
        for (int j = 0; j < 4; j++) {
            int row = m0 + wr * 64 + m * 16 + lk * 4 + j;
            if (row >= M) continue;
            const float* rb = nullptr;
            if constexpr (ROWBIAS) rb = bias + (size_t)(row / L_) * N;
#pragma unroll
            for (int n = 0; n < 4; n++) {
                int col = n0 + wc * 64 + n * 16 + lr;
                float c = acc[m][n][j];
                if constexpr (ROWBIAS) c += rb[col];
                else                   c += bv[n];
                if constexpr (RELU) c = fmaxf(c, 0.0f);
                if constexpr (RESID) c += resid[(size_t)row * N + col];
                if constexpr (OUTBF) ((u16*)Cout)[(size_t)row * N + col] = f2bf(c);
                else                 ((float*)Cout)[(size_t)row * N + col] = c;
            }
        }
    }
}

// ======================================================================
// LayerNorm: one wave per row; optional ReLU; optional bf16 output.
// ======================================================================
template<int DD, bool RELU, bool OUTBF>
__global__ __launch_bounds__(256)
void ln_k(const float* __restrict__ x, const float* __restrict__ s,
          const float* __restrict__ bb, void* __restrict__ out, int M)
{
    const int lane = threadIdx.x & 63;
    const int row = (blockIdx.x << 2) + (threadIdx.x >> 6);
    if (row >= M) return;
    const float* xr = x + (size_t)row * DD;
    constexpr int NV = DD / 64;
    float v[NV];
    if constexpr (NV == 8) {
        *(float4*)(v)     = *(const float4*)(xr + lane * 8);
        *(float4*)(v + 4) = *(const float4*)(xr + lane * 8 + 4);
    } else {
        float2 t = *(const float2*)(xr + lane * 2);
        v[0] = t.x; v[1] = t.y;
    }
    float sum = 0.f, sq = 0.f;
#pragma unroll
    for (int e = 0; e < NV; e++) { sum += v[e]; sq += v[e] * v[e]; }
#pragma unroll
    for (int msk = 1; msk < 64; msk <<= 1) {
        sum += __shfl_xor(sum, msk);
        sq  += __shfl_xor(sq, msk);
    }
    const float mean = sum * (1.0f / DD);
    const float var  = sq * (1.0f / DD) - mean * mean;
    const float rstd = rsqrtf(var + EPS_);
#pragma unroll
    for (int e = 0; e < NV; e++) {
        int d = lane * NV + e;
        float r = (v[e] - mean) * rstd * s[d] + bb[d];
        if constexpr (RELU) r = fmaxf(r, 0.0f);
        v[e] = r;
    }
    if constexpr (OUTBF) {
        u16* orow = (u16*)out + (size_t)row * DD;
        if constexpr (NV == 8) {
            s16x8 o;
#pragma unroll
            for (int e = 0; e < 8; e++) o[e] = (short)f2bf(v[e]);
            *(s16x8*)(orow + lane * 8) = o;
        } else {
            orow[lane * 2] = f2bf(v[0]); orow[lane * 2 + 1] = f2bf(v[1]);
        }
    } else {
        float* orow = (float*)out + (size_t)row * DD;
        if constexpr (NV == 8) {
            *(float4*)(orow + lane * 8)     = *(float4*)(v);
            *(float4*)(orow + lane * 8 + 4) = *(float4*)(v + 4);
        } else {
            float2 t; t.x = v[0]; t.y = v[1];
            *(float2*)(orow + lane * 2) = t;
        }
    }
}

// ======================================================================
// RoPE on bf16 [BL,512] -> bf16, 8 elems/thread
// ======================================================================
__global__ __launch_bounds__(256)
void rope_k(const u16* __restrict__ n, const float* __restrict__ ct,
            const float* __restrict__ st, u16* __restrict__ r)
{
    int t = blockIdx.x * 256 + threadIdx.x;
    if (t >= BL_ * D_ / 8) return;
    int idx = t << 3;
    int l = (idx / D_) % L_;
    int d = idx & (D_ - 1);
    int dd = d & 63;
    s16x8 xv = *(const s16x8*)(n + idx);
    int pidx; float sgn;
    if (dd < 32) { pidx = idx + 32; sgn = -1.0f; }
    else         { pidx = idx - 32; sgn =  1.0f; }
    s16x8 pv = *(const s16x8*)(n + pidx);
    float4 c0 = *(const float4*)(ct + l * DH_ + dd);
    float4 c1 = *(const float4*)(ct + l * DH_ + dd + 4);
    float4 s0 = *(const float4*)(st + l * DH_ + dd);
    float4 s1 = *(const float4*)(st + l * DH_ + dd + 4);
    float cc[8] = {c0.x,c0.y,c0.z,c0.w,c1.x,c1.y,c1.z,c1.w};
    float ss[8] = {s0.x,s0.y,s0.z,s0.w,s1.x,s1.y,s1.z,s1.w};
    s16x8 o;
#pragma unroll
    for (int e = 0; e < 8; e++) {
        float xf = bf2f((u16)xv[e]);
        float pf = bf2f((u16)pv[e]);
        o[e] = (short)f2bf(xf * cc[e] + sgn * pf * ss[e]);
    }
    *(s16x8*)(r + idx) = o;
}

// ======================================================================
// MFMA flash attention, swapped-operand, double-buffered K/V LDS,
// exp2-domain softmax (Q pre-scaled by 0.125*log2e), defer-max (THR=8).
// Per tile: stage(next tile -> alt buffer) overlaps compute(cur buffer);
// ONE barrier per tile.
// ======================================================================
__global__ __launch_bounds__(256)
void attn_k(const u16* __restrict__ qk, const u16* __restrict__ v,
            const float* __restrict__ mask, u16* __restrict__ o)
{
    constexpr int LDA = 68;
    constexpr int TSZ = 64 * LDA;
    __shared__ u16 Kt[2 * TSZ];
    __shared__ u16 Vt[2 * TSZ];
    const int bh = blockIdx.x >> 4, qt = blockIdx.x & 15;
    const int b = bh >> 3, h = bh & 7;
    const int tid = threadIdx.x;
    const int lane = tid & 63, w = tid >> 6;
    const int lr = lane & 15, lg = lane >> 4;
    const size_t basebl = (size_t)b * L_;

    // Q B-frags: lane's q-row = qt*64 + w*16 + lr (pre-scaled weights)
    const int qrow = qt * 64 + w * 16 + lr;
    const int qc = qrow < L_ ? qrow : L_ - 1;
    s16x8 bq[2];
#pragma unroll
    for (int kk = 0; kk < 2; kk++)
        bq[kk] = *(const s16x8*)(qk + (basebl + qc) * 1024 + h * DH_ + kk * 32 + lg * 8);

    f32x4 oacc[4];            // O^T: col q=lr, rows d = 16*n2 + 4*lg + j
#pragma unroll
    for (int n = 0; n < 4; n++) oacc[n] = (f32x4)0.0f;
    float m_run = -1e30f, l_run = 0.f;

    const int st_key = tid >> 3;          // 0..31 (+32 for u=1)
    const int st_d8 = (tid & 7) << 3;
    const int src0 = lr + ((lane & 16) << 1);   // lr + 32*(lg&1)
    const int src1 = src0 + 16;
    const bool ahi = (lg >> 1) != 0;

    auto stage = [&](int buf, int kt_) {
#pragma unroll
        for (int u = 0; u < 2; u++) {
            int key = st_key + u * 32;
            int gk = kt_ * 64 + key; if (gk >= L_) gk = L_ - 1;
            s16x8 kv = *(const s16x8*)(qk + (basebl + gk) * 1024 + 512 + h * DH_ + st_d8);
            s16x8 vv = *(const s16x8*)(v  + (basebl + gk) * D_ + h * DH_ + st_d8);
            *(s16x8*)&Kt[buf * TSZ + key * LDA + st_d8] = kv;
#pragma unroll
            for (int e = 0; e < 8; e++)
                Vt[buf * TSZ + (st_d8 + e) * LDA + key] = (u16)vv[e];
        }
    };

    stage(0, 0);
    __syncthreads();

    for (int kt = 0; kt < 16; kt++) {
        const int cur = kt & 1;
        // overlap: issue next tile's staging while computing this tile
        if (kt < 15) stage(cur ^ 1, kt + 1);

        // key validity via one ballot
        int gkey = kt * 64 + lane;
        bool vb = (gkey < L_) && (mask[basebl + gkey] > 0.0f);
        u64 vm = __ballot(vb);

        // S^T = K Q^T (already in exp2 domain)
        f32x4 sacc[4];
#pragma unroll
        for (int n = 0; n < 4; n++) {
            sacc[n] = (f32x4)0.0f;
#pragma unroll
            for (int kk = 0; kk < 2; kk++) {
                s16x8 ak = *(const s16x8*)&Kt[cur * TSZ + (n * 16 + lr) * LDA + kk * 32 + lg * 8];
                sacc[n] = __builtin_amdgcn_mfma_f32_16x16x32_bf16(ak, bq[kk], sacc[n], 0, 0, 0);
            }
        }

        // masked in-register max (lane holds 16 S of one q-row)
        float p[4][4];
        float tm = -1e30f;
#pragma unroll
        for (int n = 0; n < 4; n++)
#pragma unroll
            for (int j = 0; j < 4; j++) {
                int kl = 16 * n + 4 * lg + j;
                float s = ((vm >> kl) & 1ull) ? sacc[n][j] : -1e30f;
                p[n][j] = s;
                tm = fmaxf(tm, s);
            }
        tm = fmaxf(tm, __shfl_xor(tm, 16));
        tm = fmaxf(tm, __shfl_xor(tm, 32));
        // defer-max: rescale only if max grew by > 8 (p bounded by 2^8, fp32 acc ok)
        if (!__all(tm - m_run <= 8.0f)) {
            float nm = fmaxf(m_run, tm);
            float corr = exp2f(m_run - nm);
            l_run *= corr;
#pragma unroll
            for (int n = 0; n < 4; n++) oacc[n] *= corr;
            m_run = nm;
        }
        float ts = 0.f;
#pragma unroll
        for (int n = 0; n < 4; n++)
#pragma unroll
            for (int j = 0; j < 4; j++) {
                p[n][j] = exp2f(p[n][j] - m_run);
                ts += p[n][j];
            }
        ts += __shfl_xor(ts, 16);
        ts += __shfl_xor(ts, 32);
        l_run += ts;

        // pack P -> bf16 pairs; redistribute to PV B-frag layout
        u32 pk[4][2];
#pragma unroll
        for (int n = 0; n < 4; n++) {
            pk[n][0] = pack2bf(p[n][0], p[n][1]);
            pk[n][1] = pack2bf(p[n][2], p[n][3]);
        }
        u32 r0[4][2], r1[4][2];
#pragma unroll
        for (int n = 0; n < 4; n++)
#pragma unroll
            for (int i = 0; i < 2; i++) {
                r0[n][i] = (u32)__shfl((int)pk[n][i], src0);
                r1[n][i] = (u32)__shfl((int)pk[n][i], src1);
            }
#pragma unroll
        for (int kk = 0; kk < 2; kk++) {
            u32x4 bw;
            bw[0] = ahi ? r0[2 * kk + 1][0] : r0[2 * kk][0];
            bw[1] = ahi ? r0[2 * kk + 1][1] : r0[2 * kk][1];
            bw[2] = ahi ? r1[2 * kk + 1][0] : r1[2 * kk][0];
            bw[3] = ahi ? r1[2 * kk + 1][1] : r1[2 * kk][1];
            s16x8 bp = __builtin_bit_cast(s16x8, bw);
#pragma unroll
            for (int n2 = 0; n2 < 4; n2++) {
                s16x8 av = *(const s16x8*)&Vt[cur * TSZ + (n2 * 16 + lr) * LDA + kk * 32 + lg * 8];
                oacc[n2] = __builtin_amdgcn_mfma_f32_16x16x32_bf16(av, bp, oacc[n2], 0, 0, 0);
            }
        }
        __syncthreads();   // next tile staged; cur buffer reads done
    }

    // epilogue: normalize, transpose via reused Kt buf0 (wave-private rows)
    u16* Ol = &Kt[w * 16 * LDA];
    float inv = 1.0f / l_run;
#pragma unroll
    for (int n = 0; n < 4; n++)
#pragma unroll
        for (int j = 0; j < 4; j++)
            Ol[lr * LDA + 16 * n + 4 * lg + j] = f2bf(oacc[n][j] * inv);
    int orow = lane >> 2, oc = (lane & 3) * 16;
    int qg = qt * 64 + w * 16 + orow;
    if (qg < L_) {
        s16x8 o0 = *(const s16x8*)&Ol[orow * LDA + oc];
        s16x8 o1 = *(const s16x8*)&Ol[orow * LDA + oc + 8];
        *(s16x8*)(o + (basebl + qg) * D_ + h * DH_ + oc) = o0;
        *(s16x8*)(o + (basebl + qg) * D_ + h * DH_ + oc + 8) = o1;
    }
}

// ======================================================================
// masked mean pool, two-stage.
// ======================================================================
__global__ __launch_bounds__(512)
void pool1_k(const float* __restrict__ x, const float* __restrict__ mask,
             float* __restrict__ pp, float* __restrict__ mp)
{
    const int b = blockIdx.x, sp = blockIdx.y;
    const int d = threadIdx.x;
    const int l0 = sp * 64;
    float acc = 0.f;
    for (int l = l0; l < l0 + 64 && l < L_; l++)
        acc += x[((size_t)b * L_ + l) * D_ + d] * mask[b * L_ + l];
    pp[((size_t)b * 16 + sp) * D_ + d] = acc;
    if (d == 0) {
        float ms = 0.f;
        for (int l = l0; l < l0 + 64 && l < L_; l++) ms += mask[b * L_ + l];
        mp[b * 16 + sp] = ms;
    }
}

__global__ __launch_bounds__(512)
void pool2_k(const float* __restrict__ pp, const float* __restrict__ mp,
             float* __restrict__ g)
{
    const int b = blockIdx.x;
    const int d = threadIdx.x;
    float acc = 0.f, ms = 0.f;
#pragma unroll
    for (int sp = 0; sp < 16; sp++) {
        acc += pp[((size_t)b * 16 + sp) * D_ + d];
        ms += mp[b * 16 + sp];
    }
    g[b * D_ + d] = acc / ms;
}

// ======================================================================
// gpart[b][j] = h1_b[j] + dot(gctx[b], h1_w[j, 512:1024])  (fp32)
// ======================================================================
__global__ __launch_bounds__(256)
void gpart_k(const float* __restrict__ g, const float* __restrict__ h1w,
             const float* __restrict__ h1b, float* __restrict__ gp)
{
    const int lane = threadIdx.x & 63;
    const int gid = (blockIdx.x << 2) + (threadIdx.x >> 6);
    const int b = gid >> 7, j = gid & 127;
    const float* wr = h1w + (size_t)j * (2 * D_) + D_;
    const float* gr = g + b * D_;
    float4 a0 = *(const float4*)(gr + lane * 8);
    float4 a1 = *(const float4*)(gr + lane * 8 + 4);
    float4 w0 = *(const float4*)(wr + lane * 8);
    float4 w1v = *(const float4*)(wr + lane * 8 + 4);
    float acc = a0.x * w0.x + a0.y * w0.y + a0.z * w0.z + a0.w * w0.w
              + a1.x * w1v.x + a1.y * w1v.y + a1.z * w1v.z + a1.w * w1v.w;
#pragma unroll
    for (int msk = 1; msk < 64; msk <<= 1) acc += __shfl_xor(acc, msk);
    if (lane == 0) gp[b * 128 + j] = acc + h1b[j];
}

// ======================================================================
// logits[m] = h2_b + dot(h[m,0:128], h2_w)
// ======================================================================
__global__ __launch_bounds__(256)
void logits_k(const float* __restrict__ h, const float* __restrict__ w,
              const float* __restrict__ bsc, float* __restrict__ out, int M)
{
    const int lane = threadIdx.x & 63;
    const int row = (blockIdx.x << 2) + (threadIdx.x >> 6);
    if (row >= M) return;
    float2 hv = *(const float2*)(h + (size_t)row * 128 + lane * 2);
    float2 wv = *(const float2*)(w + lane * 2);
    float acc = hv.x * wv.x + hv.y * wv.y;
#pragma unroll
    for (int msk = 1; msk < 64; msk <<= 1) acc += __shfl_xor(acc, msk);
    if (lane == 0) out[row] = acc + bsc[0];
}

// ======================================================================
// host orchestration
// ======================================================================
extern "C" void kernel_launch(void* const* d_in, const int* in_sizes, int n_in,
                              void* d_out, int out_size, void* d_ws, size_t ws_size,
                              hipStream_t stream)
{
    const float* emb       = (const float*)d_in[0];
    const float* mask      = (const float*)d_in[1];
    const float* proj_w    = (const float*)d_in[3];
    const float* proj_b    = (const float*)d_in[4];
    const float* proj_ln_s = (const float*)d_in[5];
    const float* proj_ln_b = (const float*)d_in[6];
    const float* ln1_s     = (const float*)d_in[7];
    const float* ln1_b     = (const float*)d_in[8];
    const float* in_w      = (const float*)d_in[9];
    const float* in_b      = (const float*)d_in[10];
    const float* out_w     = (const float*)d_in[11];
    const float* out_b     = (const float*)d_in[12];
    const float* ln2_s     = (const float*)d_in[13];
    const float* ln2_b     = (const float*)d_in[14];
    const float* w1        = (const float*)d_in[15];
    const float* b1        = (const float*)d_in[16];
    const float* w2        = (const float*)d_in[17];
    const float* b2        = (const float*)d_in[18];
    const float* h1_w      = (const float*)d_in[19];
    const float* h1_b      = (const float*)d_in[20];
    const float* hln_s     = (const float*)d_in[21];
    const float* hln_b     = (const float*)d_in[22];
    const float* h2_w      = (const float*)d_in[23];
    const float* h2_b      = (const float*)d_in[24];
    float* out = (float*)d_out;

    // Workspace map (S = BL*D floats):
    //   [0,S)      X fp32 residual
    //   [S,2S)     Rf fp32 (proj-out, head Hb) / QKB bf16 [BL,1024] (disjoint)
    //   [2S,2.5S)  VB bf16
    //   [2.5S,3S)  NbB bf16
    //   [3S,5S)    FFb16 bf16 [BL,2048]; aliases embB, RopeB, RB (disjoint)
    //   [5S,...)   bf16 weights, CT/ST/GC/GP/Pp/Mp/QBS
    float* ws = (float*)d_ws;
    const size_t S = (size_t)BL_ * D_;
    float* X  = ws;
    float* Rf = ws + S;
    u16* QKB   = (u16*)(ws + S);
    u16* VB    = (u16*)(ws + 2 * S);
    u16* NbB   = (u16*)(ws + 2 * S) + S;
    u16* FFb16 = (u16*)(ws + 3 * S);
    u16* RopeB = FFb16;
    u16* embB  = FFb16;
    u16* RB    = (u16*)(ws + 4 * S);
    u16* projwB = (u16*)(ws + 5 * S);
    u16* iwB  = projwB + 512 * 1280;
    u16* owB  = iwB + (size_t)NL_ * 3 * D_ * D_;
    u16* w1B  = owB + (size_t)NL_ * D_ * D_;
    u16* w2B  = w1B + (size_t)NL_ * FF_ * D_;
    u16* h1wB = w2B + (size_t)NL_ * D_ * FF_;
    float* CT = ws + 5 * S + 6651904;
    float* ST = CT + L_ * DH_;
    float* GC = ST + L_ * DH_;
    float* GP = GC + B_ * D_;
    float* Pp = GP + B_ * 128;            // [B*16, 512] partials
    float* Mp = Pp + (size_t)B_ * 16 * D_;
    float* QBS = Mp + B_ * 16;            // [NL,1024] scaled q/k bias
    float* Hb = Rf;

    const int MT = 128;
    const dim3 blk(256);
    const int lnGrid = (BL_ + 3) / 4;

    cast_k<<<(BL_ * E_ / 8 + 255) / 256, blk, 0, stream>>>(emb, embB, BL_ * E_ / 8);
    cast_k<<<(512 * 1280 / 8 + 255) / 256, blk, 0, stream>>>(proj_w, projwB, 512 * 1280 / 8);
    castq_k<<<(NL_ * 3 * D_ * D_ / 8 + 255) / 256, blk, 0, stream>>>(in_w, iwB, NL_ * 3 * D_ * D_ / 8);
    qbias_k<<<(NL_ * 1024 + 255) / 256, blk, 0, stream>>>(in_b, QBS);
    cast_k<<<(NL_ * D_ * D_ / 8 + 255) / 256, blk, 0, stream>>>(out_w, owB, NL_ * D_ * D_ / 8);
    cast_k<<<(NL_ * FF_ * D_ / 8 + 255) / 256, blk, 0, stream>>>(w1, w1B, NL_ * FF_ * D_ / 8);
    cast_k<<<(NL_ * D_ * FF_ / 8 + 255) / 256, blk, 0, stream>>>(w2, w2B, NL_ * D_ * FF_ / 8);
    h1cast_k<<<(128 * 512 / 8 + 255) / 256, blk, 0, stream>>>(h1_w, h1wB);
    tables_k<<<(L_ * DH_ + 255) / 256, blk, 0, stream>>>(CT, ST);

    mgemm_k<false,false,false,false><<<MT * (D_ / 128), blk, 0, stream>>>(
        embB, projwB, proj_b, nullptr, Rf, BL_, D_, E_);
    ln_k<D_,false,false><<<lnGrid, blk, 0, stream>>>(Rf, proj_ln_s, proj_ln_b, X, BL_);

    for (int i = 0; i < NL_; i++) {
        const u16* iw = iwB + (size_t)i * 3 * D_ * D_;
        const float* ib = in_b + (size_t)i * 3 * D_;
        ln_k<D_,false,true><<<lnGrid, blk, 0, stream>>>(X, ln1_s + i * D_, ln1_b + i * D_, NbB, BL_);
        mgemm_k<false,false,true,false><<<MT * 4, blk, 0, stream>>>(
            NbB, iw + 2 * D_ * D_, ib + 2 * D_, nullptr, VB, BL_, D_, D_);
        rope_k<<<(BL_ * D_ / 8 + 255) / 256, blk, 0, stream>>>(NbB, CT, ST, RopeB);
        // fused q+k projection (wq pre-scaled by QSC_, bias = QBS[i])
        mgemm_k<false,false,true,false><<<MT * 8, blk, 0, stream>>>(
            RopeB, iw, QBS + (size_t)i * 1024, nullptr, QKB, BL_, 1024, D_);
        attn_k<<<B_ * H_ * 16, blk, 0, stream>>>(QKB, VB, mask, RB);
        mgemm_k<false,true,false,false><<<MT * 4, blk, 0, stream>>>(
            RB, owB + (size_t)i * D_ * D_, out_b + i * D_, X, X, BL_, D_, D_);
        ln_k<D_,false,true><<<lnGrid, blk, 0, stream>>>(X, ln2_s + i * D_, ln2_b + i * D_, NbB, BL_);
        mgemm_k<true,false,true,false><<<MT * 16, blk, 0, stream>>>(
            NbB, w1B + (size_t)i * FF_ * D_, b1 + i * FF_, nullptr, FFb16, BL_, FF_, D_);
        mgemm_k<false,true,false,false><<<MT * 4, blk, 0, stream>>>(
            FFb16, w2B + (size_t)i * D_ * FF_, b2 + i * D_, X, X, BL_, D_, FF_);
    }

    pool1_k<<<dim3(B_, 16), dim3(512), 0, stream>>>(X, mask, Pp, Mp);
    pool2_k<<<B_, dim3(512), 0, stream>>>(Pp, Mp, GC);
    gpart_k<<<(B_ * 128) / 4, blk, 0, stream>>>(GC, h1_w, h1_b, GP);
    cast_k<<<(int)((S / 8 + 255) / 256), blk, 0, stream>>>(X, NbB, (int)(S / 8));
    mgemm_k<false,false,false,true><<<MT * 1, blk, 0, stream>>>(
        NbB, h1wB, GP, nullptr, Hb, BL_, 128, D_);
    ln_k<128,true,false><<<lnGrid, blk, 0, stream>>>(Hb, hln_s, hln_b, Hb, BL_);
    logits_k<<<lnGrid, blk, 0, stream>>>(Hb, h2_w, h2_b, out, BL_);
}

// Round 10
// 1484.825 us; speedup vs baseline: 1.0107x; 1.0107x over previous
//
#include <hip/hip_runtime.h>
#include <cstdint>
#include <cstddef>

// ---------------- problem constants ----------------
#define B_   16
#define L_   1022
#define E_   1280
#define D_   512
#define H_   8
#define FF_  2048
#define NL_  4
#define DH_  64
#define BL_  (B_*L_)      // 16352
#define EPS_ 1e-5f
#define QSC_ 0.18033688011112042f   // 0.125 * log2(e)

typedef unsigned short u16;
typedef unsigned int   u32;
typedef unsigned long long u64;
typedef float f32x4 __attribute__((ext_vector_type(4)));
typedef short s16x8 __attribute__((ext_vector_type(8)));
typedef u32 u32x4 __attribute__((ext_vector_type(4)));

__device__ __forceinline__ u16 f2bf(float f) {
    u32 u = __builtin_bit_cast(u32, f);
    u += 0x7fffu + ((u >> 16) & 1u);
    return (u16)(u >> 16);
}
__device__ __forceinline__ float bf2f(u16 u) {
    return __builtin_bit_cast(float, (u32)u << 16);
}
__device__ __forceinline__ u32 pack2bf(float a, float b) {
    return (u32)f2bf(a) | ((u32)f2bf(b) << 16);
}

// ======================================================================
// fp32 -> bf16 cast, 8 elems/thread
// ======================================================================
__global__ __launch_bounds__(256)
void cast_k(const float* __restrict__ src, u16* __restrict__ dst, int n8) {
    int t = blockIdx.x * 256 + threadIdx.x;
    if (t >= n8) return;
    const float* s = src + (size_t)t * 8;
    float4 a = *(const float4*)(s);
    float4 b = *(const float4*)(s + 4);
    s16x8 o;
    o[0] = (short)f2bf(a.x); o[1] = (short)f2bf(a.y);
    o[2] = (short)f2bf(a.z); o[3] = (short)f2bf(a.w);
    o[4] = (short)f2bf(b.x); o[5] = (short)f2bf(b.y);
    o[6] = (short)f2bf(b.z); o[7] = (short)f2bf(b.w);
    *(s16x8*)(dst + (size_t)t * 8) = o;
}

// in_w cast with wq rows (row%1536 < 512) pre-scaled by QSC_ (exp2-domain
// softmax: folds 1/sqrt(DH) * log2(e) into the Q projection)
__global__ __launch_bounds__(256)
void castq_k(const float* __restrict__ src, u16* __restrict__ dst, int n8) {
    int t = blockIdx.x * 256 + threadIdx.x;
    if (t >= n8) return;
    int row = t >> 6;                  // 512 cols / 8 per chunk
    float sc = (row % 1536) < 512 ? QSC_ : 1.0f;
    const float* s = src + (size_t)t * 8;
    float4 a = *(const float4*)(s);
    float4 b = *(const float4*)(s + 4);
    s16x8 o;
    o[0] = (short)f2bf(a.x * sc); o[1] = (short)f2bf(a.y * sc);
    o[2] = (short)f2bf(a.z * sc); o[3] = (short)f2bf(a.w * sc);
    o[4] = (short)f2bf(b.x * sc); o[5] = (short)f2bf(b.y * sc);
    o[6] = (short)f2bf(b.z * sc); o[7] = (short)f2bf(b.w * sc);
    *(s16x8*)(dst + (size_t)t * 8) = o;
}

// scaled q/k bias: qbs[i][j] = in_b[i*1536+j] * (j<512?QSC:1)
__global__ __launch_bounds__(256)
void qbias_k(const float* __restrict__ ib, float* __restrict__ qbs) {
    int t = blockIdx.x * 256 + threadIdx.x;
    if (t >= NL_ * 1024) return;
    int i = t >> 10, j = t & 1023;
    float sc = j < 512 ? QSC_ : 1.0f;
    qbs[t] = ib[i * 1536 + j] * sc;
}

// h1_w left half [128, 0:512] (row stride 1024) -> packed bf16 [128,512]
__global__ __launch_bounds__(256)
void h1cast_k(const float* __restrict__ src, u16* __restrict__ dst) {
    int t = blockIdx.x * 256 + threadIdx.x;
    if (t >= 128 * 512 / 8) return;
    int row = t >> 6, c8 = (t & 63) << 3;
    const float* s = src + (size_t)row * 1024 + c8;
    float4 a = *(const float4*)(s);
    float4 b = *(const float4*)(s + 4);
    s16x8 o;
    o[0] = (short)f2bf(a.x); o[1] = (short)f2bf(a.y);
    o[2] = (short)f2bf(a.z); o[3] = (short)f2bf(a.w);
    o[4] = (short)f2bf(b.x); o[5] = (short)f2bf(b.y);
    o[6] = (short)f2bf(b.z); o[7] = (short)f2bf(b.w);
    *(s16x8*)(dst + (size_t)row * 512 + c8) = o;
}

// ======================================================================
// RoPE cos/sin tables
// ======================================================================
__global__ void tables_k(float* __restrict__ ct, float* __restrict__ st) {
    int idx = blockIdx.x * blockDim.x + threadIdx.x;
    if (idx >= L_ * DH_) return;
    int l = idx / DH_;
    int d = idx % DH_;
    int j = d & 31;
    float invf = powf(10000.0f, -(float)(2 * j) / (float)DH_);
    float ang = (float)l * invf;
    ct[idx] = cosf(ang);
    st[idx] = sinf(ang);
}

// ======================================================================
// bf16 MFMA GEMM (reg-staged): C = act(A @ W^T + bias)(+resid bf16)
// 128x128 tile, BK=64, 256 threads (4 waves 2x2), 4x4 16x16 frags/wave.
// ======================================================================
template<bool RELU, bool RESID, bool OUTBF, bool ROWBIAS>
__global__ __launch_bounds__(256)
void mgemm_k(const u16* __restrict__ A, const u16* __restrict__ W,
             const float* __restrict__ bias, const u16* __restrict__ resid,
             void* __restrict__ Cout, int M, int N, int K)
{
    constexpr int LDT = 72;               // padded LDS row stride (bf16)
    __shared__ u16 As[128 * LDT];
    __shared__ u16 Ws[128 * LDT];
    const int nt = N >> 7;
    const int bx = blockIdx.x % nt;
    const int by = blockIdx.x / nt;
    const int m0 = by << 7, n0 = bx << 7;
    const int tid = threadIdx.x;
    const int lane = tid & 63, wid = tid >> 6;
    const int wr = wid >> 1, wc = wid & 1;
    const int lr = lane & 15, lk = lane >> 4;

    f32x4 acc[4][4];
#pragma unroll
    for (int m = 0; m < 4; m++)
#pragma unroll
        for (int n = 0; n < 4; n++) acc[m][n] = (f32x4)0.0f;

    for (int k0 = 0; k0 < K; k0 += 64) {
        s16x8 va[4], vw[4];
#pragma unroll
        for (int u = 0; u < 4; u++) {
            int ch = tid + (u << 8);          // 16B chunk id, 0..1023
            int r = ch >> 3, c8 = (ch & 7) << 3;
            int ar = m0 + r; if (ar >= M) ar = M - 1;
            va[u] = *(const s16x8*)(A + (size_t)ar * K + k0 + c8);
            vw[u] = *(const s16x8*)(W + (size_t)(n0 + r) * K + k0 + c8);
        }
        __syncthreads();   // previous iteration's LDS reads complete
#pragma unroll
        for (int u = 0; u < 4; u++) {
            int ch = tid + (u << 8);
            int r = ch >> 3, c8 = (ch & 7) << 3;
            *(s16x8*)&As[r * LDT + c8] = va[u];
            *(s16x8*)&Ws[r * LDT + c8] = vw[u];
        }
        __syncthreads();   // tiles staged
#pragma unroll
        for (int kk = 0; kk < 2; kk++) {
            s16x8 af[4], bf[4];
#pragma unroll
            for (int m = 0; m < 4; m++)
                af[m] = *(const s16x8*)&As[(wr * 64 + m * 16 + lr) * LDT + kk * 32 + lk * 8];
#pragma unroll
            for (int n = 0; n < 4; n++)
                bf[n] = *(const s16x8*)&Ws[(wc * 64 + n * 16 + lr) * LDT + kk * 32 + lk * 8];
#pragma unroll
            for (int m = 0; m < 4; m++)
#pragma unroll
                for (int n = 0; n < 4; n++)
                    acc[m][n] = __builtin_amdgcn_mfma_f32_16x16x32_bf16(
                        af[m], bf[n], acc[m][n], 0, 0, 0);
        }
    }

    float bv[4];
    if constexpr (!ROWBIAS) {
#pragma unroll
        for (int n = 0; n < 4; n++) bv[n] = bias[n0 + wc * 64 + n * 16 + lr];
    }
#pragma unroll
    for (int m = 0; m < 4; m++) {
#pragma unroll
        for (int j = 0; j < 4; j++) {
            int row = m0 + wr * 64 + m * 16 + lk * 4 + j;
            if (row >= M) continue;
            const float* rb = nullptr;
            if constexpr (ROWBIAS) rb = bias + (size_t)(row / L_) * N;
#pragma unroll
            for (int n = 0; n < 4; n++) {
                int col = n0 + wc * 64 + n * 16 + lr;
                float c = acc[m][n][j];
                if constexpr (ROWBIAS) c += rb[col];
                else                   c += bv[n];
                if constexpr (RELU) c = fmaxf(c, 0.0f);
                if constexpr (RESID) c += bf2f(resid[(size_t)row * N + col]);
                if constexpr (OUTBF) ((u16*)Cout)[(size_t)row * N + col] = f2bf(c);
                else                 ((float*)Cout)[(size_t)row * N + col] = c;
            }
        }
    }
}

// ======================================================================
// LayerNorm: one wave per row; RELU / bf16-out / bf16-in options.
// ======================================================================
template<int DD, bool RELU, bool OUTBF, bool INBF>
__global__ __launch_bounds__(256)
void ln_k(const void* __restrict__ xin, const float* __restrict__ s,
          const float* __restrict__ bb, void* __restrict__ out, int M)
{
    const int lane = threadIdx.x & 63;
    const int row = (blockIdx.x << 2) + (threadIdx.x >> 6);
    if (row >= M) return;
    constexpr int NV = DD / 64;
    float v[NV];
    if constexpr (INBF) {
        const u16* xr = (const u16*)xin + (size_t)row * DD;
        if constexpr (NV == 8) {
            s16x8 t = *(const s16x8*)(xr + lane * 8);
#pragma unroll
            for (int e = 0; e < 8; e++) v[e] = bf2f((u16)t[e]);
        } else {
            v[0] = bf2f(xr[lane * 2]); v[1] = bf2f(xr[lane * 2 + 1]);
        }
    } else {
        const float* xr = (const float*)xin + (size_t)row * DD;
        if constexpr (NV == 8) {
            *(float4*)(v)     = *(const float4*)(xr + lane * 8);
            *(float4*)(v + 4) = *(const float4*)(xr + lane * 8 + 4);
        } else {
            float2 t = *(const float2*)(xr + lane * 2);
            v[0] = t.x; v[1] = t.y;
        }
    }
    float sum = 0.f, sq = 0.f;
#pragma unroll
    for (int e = 0; e < NV; e++) { sum += v[e]; sq += v[e] * v[e]; }
#pragma unroll
    for (int msk = 1; msk < 64; msk <<= 1) {
        sum += __shfl_xor(sum, msk);
        sq  += __shfl_xor(sq, msk);
    }
    const float mean = sum * (1.0f / DD);
    const float var  = sq * (1.0f / DD) - mean * mean;
    const float rstd = rsqrtf(var + EPS_);
#pragma unroll
    for (int e = 0; e < NV; e++) {
        int d = lane * NV + e;
        float r = (v[e] - mean) * rstd * s[d] + bb[d];
        if constexpr (RELU) r = fmaxf(r, 0.0f);
        v[e] = r;
    }
    if constexpr (OUTBF) {
        u16* orow = (u16*)out + (size_t)row * DD;
        if constexpr (NV == 8) {
            s16x8 o;
#pragma unroll
            for (int e = 0; e < 8; e++) o[e] = (short)f2bf(v[e]);
            *(s16x8*)(orow + lane * 8) = o;
        } else {
            orow[lane * 2] = f2bf(v[0]); orow[lane * 2 + 1] = f2bf(v[1]);
        }
    } else {
        float* orow = (float*)out + (size_t)row * DD;
        if constexpr (NV == 8) {
            *(float4*)(orow + lane * 8)     = *(float4*)(v);
            *(float4*)(orow + lane * 8 + 4) = *(float4*)(v + 4);
        } else {
            float2 t; t.x = v[0]; t.y = v[1];
            *(float2*)(orow + lane * 2) = t;
        }
    }
}

// ======================================================================
// RoPE on bf16 [BL,512] -> bf16, 8 elems/thread
// ======================================================================
__global__ __launch_bounds__(256)
void rope_k(const u16* __restrict__ n, const float* __restrict__ ct,
            const float* __restrict__ st, u16* __restrict__ r)
{
    int t = blockIdx.x * 256 + threadIdx.x;
    if (t >= BL_ * D_ / 8) return;
    int idx = t << 3;
    int l = (idx / D_) % L_;
    int d = idx & (D_ - 1);
    int dd = d & 63;
    s16x8 xv = *(const s16x8*)(n + idx);
    int pidx; float sgn;
    if (dd < 32) { pidx = idx + 32; sgn = -1.0f; }
    else         { pidx = idx - 32; sgn =  1.0f; }
    s16x8 pv = *(const s16x8*)(n + pidx);
    float4 c0 = *(const float4*)(ct + l * DH_ + dd);
    float4 c1 = *(const float4*)(ct + l * DH_ + dd + 4);
    float4 s0 = *(const float4*)(st + l * DH_ + dd);
    float4 s1 = *(const float4*)(st + l * DH_ + dd + 4);
    float cc[8] = {c0.x,c0.y,c0.z,c0.w,c1.x,c1.y,c1.z,c1.w};
    float ss[8] = {s0.x,s0.y,s0.z,s0.w,s1.x,s1.y,s1.z,s1.w};
    s16x8 o;
#pragma unroll
    for (int e = 0; e < 8; e++) {
        float xf = bf2f((u16)xv[e]);
        float pf = bf2f((u16)pv[e]);
        o[e] = (short)f2bf(xf * cc[e] + sgn * pf * ss[e]);
    }
    *(s16x8*)(r + idx) = o;
}

// ======================================================================
// MFMA flash attention, swapped-operand, r8 two-barrier structure,
// exp2-domain softmax (Q pre-scaled), defer-max (THR=8).
// ======================================================================
__global__ __launch_bounds__(256)
void attn_k(const u16* __restrict__ qk, const u16* __restrict__ v,
            const float* __restrict__ mask, u16* __restrict__ o)
{
    constexpr int LDA = 68;
    __shared__ u16 Kt[64 * LDA];
    __shared__ u16 Vt[64 * LDA];
    const int bh = blockIdx.x >> 4, qt = blockIdx.x & 15;
    const int b = bh >> 3, h = bh & 7;
    const int tid = threadIdx.x;
    const int lane = tid & 63, w = tid >> 6;
    const int lr = lane & 15, lg = lane >> 4;
    const size_t basebl = (size_t)b * L_;

    // Q B-frags: lane's q-row = qt*64 + w*16 + lr (pre-scaled weights)
    const int qrow = qt * 64 + w * 16 + lr;
    const int qc = qrow < L_ ? qrow : L_ - 1;
    s16x8 bq[2];
#pragma unroll
    for (int kk = 0; kk < 2; kk++)
        bq[kk] = *(const s16x8*)(qk + (basebl + qc) * 1024 + h * DH_ + kk * 32 + lg * 8);

    f32x4 oacc[4];            // O^T: col q=lr, rows d = 16*n2 + 4*lg + j
#pragma unroll
    for (int n = 0; n < 4; n++) oacc[n] = (f32x4)0.0f;
    float m_run = -1e30f, l_run = 0.f;

    const int st_key = tid >> 3;          // 0..31 (+32 for u=1)
    const int st_d8 = (tid & 7) << 3;
    const int src0 = lr + ((lane & 16) << 1);   // lr + 32*(lg&1)
    const int src1 = src0 + 16;
    const bool ahi = (lg >> 1) != 0;

    for (int kt = 0; kt < 16; kt++) {
        __syncthreads();          // all waves done reading prev Kt/Vt
#pragma unroll
        for (int u = 0; u < 2; u++) {
            int key = st_key + u * 32;
            int gk = kt * 64 + key; if (gk >= L_) gk = L_ - 1;
            s16x8 kv = *(const s16x8*)(qk + (basebl + gk) * 1024 + 512 + h * DH_ + st_d8);
            s16x8 vv = *(const s16x8*)(v  + (basebl + gk) * D_ + h * DH_ + st_d8);
            *(s16x8*)&Kt[key * LDA + st_d8] = kv;
#pragma unroll
            for (int e = 0; e < 8; e++) Vt[(st_d8 + e) * LDA + key] = (u16)vv[e];
        }
        __syncthreads();

        // key validity via one ballot
        int gkey = kt * 64 + lane;
        bool vb = (gkey < L_) && (mask[basebl + gkey] > 0.0f);
        u64 vm = __ballot(vb);

        // S^T = K Q^T (exp2 domain)
        f32x4 sacc[4];
#pragma unroll
        for (int n = 0; n < 4; n++) {
            sacc[n] = (f32x4)0.0f;
#pragma unroll
            for (int kk = 0; kk < 2; kk++) {
                s16x8 ak = *(const s16x8*)&Kt[(n * 16 + lr) * LDA + kk * 32 + lg * 8];
                sacc[n] = __builtin_amdgcn_mfma_f32_16x16x32_bf16(ak, bq[kk], sacc[n], 0, 0, 0);
            }
        }

        // masked in-register max (lane holds 16 S of one q-row)
        float p[4][4];
        float tm = -1e30f;
#pragma unroll
        for (int n = 0; n < 4; n++)
#pragma unroll
            for (int j = 0; j < 4; j++) {
                int kl = 16 * n + 4 * lg + j;
                float s = ((vm >> kl) & 1ull) ? sacc[n][j] : -1e30f;
                p[n][j] = s;
                tm = fmaxf(tm, s);
            }
        tm = fmaxf(tm, __shfl_xor(tm, 16));
        tm = fmaxf(tm, __shfl_xor(tm, 32));
        // defer-max: rescale only if max grew by > 8 (p <= 2^8, fp32 acc ok)
        if (!__all(tm - m_run <= 8.0f)) {
            float nm = fmaxf(m_run, tm);
            float corr = exp2f(m_run - nm);
            l_run *= corr;
#pragma unroll
            for (int n = 0; n < 4; n++) oacc[n] *= corr;
            m_run = nm;
        }
        float ts = 0.f;
#pragma unroll
        for (int n = 0; n < 4; n++)
#pragma unroll
            for (int j = 0; j < 4; j++) {
                p[n][j] = exp2f(p[n][j] - m_run);
                ts += p[n][j];
            }
        ts += __shfl_xor(ts, 16);
        ts += __shfl_xor(ts, 32);
        l_run += ts;

        // pack P -> bf16 pairs; redistribute to PV B-frag layout
        u32 pk[4][2];
#pragma unroll
        for (int n = 0; n < 4; n++) {
            pk[n][0] = pack2bf(p[n][0], p[n][1]);
            pk[n][1] = pack2bf(p[n][2], p[n][3]);
        }
        u32 r0[4][2], r1[4][2];
#pragma unroll
        for (int n = 0; n < 4; n++)
#pragma unroll
            for (int i = 0; i < 2; i++) {
                r0[n][i] = (u32)__shfl((int)pk[n][i], src0);
                r1[n][i] = (u32)__shfl((int)pk[n][i], src1);
            }
#pragma unroll
        for (int kk = 0; kk < 2; kk++) {
            u32x4 bw;
            bw[0] = ahi ? r0[2 * kk + 1][0] : r0[2 * kk][0];
            bw[1] = ahi ? r0[2 * kk + 1][1] : r0[2 * kk][1];
            bw[2] = ahi ? r1[2 * kk + 1][0] : r1[2 * kk][0];
            bw[3] = ahi ? r1[2 * kk + 1][1] : r1[2 * kk][1];
            s16x8 bp = __builtin_bit_cast(s16x8, bw);
#pragma unroll
            for (int n2 = 0; n2 < 4; n2++) {
                s16x8 av = *(const s16x8*)&Vt[(n2 * 16 + lr) * LDA + kk * 32 + lg * 8];
                oacc[n2] = __builtin_amdgcn_mfma_f32_16x16x32_bf16(av, bp, oacc[n2], 0, 0, 0);
            }
        }
    }

    // epilogue: normalize, transpose via reused Kt (wave-private 16 rows)
    __syncthreads();   // all waves done with Kt/Vt MFMA reads
    u16* Ol = &Kt[w * 16 * LDA];
    float inv = 1.0f / l_run;
#pragma unroll
    for (int n = 0; n < 4; n++)
#pragma unroll
        for (int j = 0; j < 4; j++)
            Ol[lr * LDA + 16 * n + 4 * lg + j] = f2bf(oacc[n][j] * inv);
    int orow = lane >> 2, oc = (lane & 3) * 16;
    int qg = qt * 64 + w * 16 + orow;
    if (qg < L_) {
        s16x8 o0 = *(const s16x8*)&Ol[orow * LDA + oc];
        s16x8 o1 = *(const s16x8*)&Ol[orow * LDA + oc + 8];
        *(s16x8*)(o + (basebl + qg) * D_ + h * DH_ + oc) = o0;
        *(s16x8*)(o + (basebl + qg) * D_ + h * DH_ + oc + 8) = o1;
    }
}

// ======================================================================
// masked mean pool, two-stage (X bf16).
// ======================================================================
__global__ __launch_bounds__(512)
void pool1_k(const u16* __restrict__ x, const float* __restrict__ mask,
             float* __restrict__ pp, float* __restrict__ mp)
{
    const int b = blockIdx.x, sp = blockIdx.y;
    const int d = threadIdx.x;
    const int l0 = sp * 64;
    float acc = 0.f;
    for (int l = l0; l < l0 + 64 && l < L_; l++)
        acc += bf2f(x[((size_t)b * L_ + l) * D_ + d]) * mask[b * L_ + l];
    pp[((size_t)b * 16 + sp) * D_ + d] = acc;
    if (d == 0) {
        float ms = 0.f;
        for (int l = l0; l < l0 + 64 && l < L_; l++) ms += mask[b * L_ + l];
        mp[b * 16 + sp] = ms;
    }
}

__global__ __launch_bounds__(512)
void pool2_k(const float* __restrict__ pp, const float* __restrict__ mp,
             float* __restrict__ g)
{
    const int b = blockIdx.x;
    const int d = threadIdx.x;
    float acc = 0.f, ms = 0.f;
#pragma unroll
    for (int sp = 0; sp < 16; sp++) {
        acc += pp[((size_t)b * 16 + sp) * D_ + d];
        ms += mp[b * 16 + sp];
    }
    g[b * D_ + d] = acc / ms;
}

// ======================================================================
// gpart[b][j] = h1_b[j] + dot(gctx[b], h1_w[j, 512:1024])  (fp32)
// ======================================================================
__global__ __launch_bounds__(256)
void gpart_k(const float* __restrict__ g, const float* __restrict__ h1w,
             const float* __restrict__ h1b, float* __restrict__ gp)
{
    const int lane = threadIdx.x & 63;
    const int gid = (blockIdx.x << 2) + (threadIdx.x >> 6);
    const int b = gid >> 7, j = gid & 127;
    const float* wr = h1w + (size_t)j * (2 * D_) + D_;
    const float* gr = g + b * D_;
    float4 a0 = *(const float4*)(gr + lane * 8);
    float4 a1 = *(const float4*)(gr + lane * 8 + 4);
    float4 w0 = *(const float4*)(wr + lane * 8);
    float4 w1v = *(const float4*)(wr + lane * 8 + 4);
    float acc = a0.x * w0.x + a0.y * w0.y + a0.z * w0.z + a0.w * w0.w
              + a1.x * w1v.x + a1.y * w1v.y + a1.z * w1v.z + a1.w * w1v.w;
#pragma unroll
    for (int msk = 1; msk < 64; msk <<= 1) acc += __shfl_xor(acc, msk);
    if (lane == 0) gp[b * 128 + j] = acc + h1b[j];
}

// ======================================================================
// logits[m] = h2_b + dot(h[m,0:128], h2_w)
// ======================================================================
__global__ __launch_bounds__(256)
void logits_k(const float* __restrict__ h, const float* __restrict__ w,
              const float* __restrict__ bsc, float* __restrict__ out, int M)
{
    const int lane = threadIdx.x & 63;
    const int row = (blockIdx.x << 2) + (threadIdx.x >> 6);
    if (row >= M) return;
    float2 hv = *(const float2*)(h + (size_t)row * 128 + lane * 2);
    float2 wv = *(const float2*)(w + lane * 2);
    float acc = hv.x * wv.x + hv.y * wv.y;
#pragma unroll
    for (int msk = 1; msk < 64; msk <<= 1) acc += __shfl_xor(acc, msk);
    if (lane == 0) out[row] = acc + bsc[0];
}

// ======================================================================
// host orchestration
// ======================================================================
extern "C" void kernel_launch(void* const* d_in, const int* in_sizes, int n_in,
                              void* d_out, int out_size, void* d_ws, size_t ws_size,
                              hipStream_t stream)
{
    const float* emb       = (const float*)d_in[0];
    const float* mask      = (const float*)d_in[1];
    const float* proj_w    = (const float*)d_in[3];
    const float* proj_b    = (const float*)d_in[4];
    const float* proj_ln_s = (const float*)d_in[5];
    const float* proj_ln_b = (const float*)d_in[6];
    const float* ln1_s     = (const float*)d_in[7];
    const float* ln1_b     = (const float*)d_in[8];
    const float* in_w      = (const float*)d_in[9];
    const float* in_b      = (const float*)d_in[10];
    const float* out_w     = (const float*)d_in[11];
    const float* out_b     = (const float*)d_in[12];
    const float* ln2_s     = (const float*)d_in[13];
    const float* ln2_b     = (const float*)d_in[14];
    const float* w1        = (const float*)d_in[15];
    const float* b1        = (const float*)d_in[16];
    const float* w2        = (const float*)d_in[17];
    const float* b2        = (const float*)d_in[18];
    const float* h1_w      = (const float*)d_in[19];
    const float* h1_b      = (const float*)d_in[20];
    const float* hln_s     = (const float*)d_in[21];
    const float* hln_b     = (const float*)d_in[22];
    const float* h2_w      = (const float*)d_in[23];
    const float* h2_b      = (const float*)d_in[24];
    float* out = (float*)d_out;

    // Workspace map (S = BL*D floats):
    //   [0,0.5S)   X bf16 residual stream [BL,512]
    //   [S,2S)     Rf fp32 (proj-out, head Hb) / QKB bf16 [BL,1024] (disjoint)
    //   [2S,2.5S)  VB bf16
    //   [2.5S,3S)  NbB bf16
    //   [3S,5S)    FFb16 bf16 [BL,2048]; aliases embB, RopeB, RB (disjoint)
    //   [5S,...)   bf16 weights, CT/ST/GC/GP/Pp/Mp/QBS
    float* ws = (float*)d_ws;
    const size_t S = (size_t)BL_ * D_;
    u16* X = (u16*)ws;                    // bf16 residual
    float* Rf = ws + S;
    u16* QKB   = (u16*)(ws + S);
    u16* VB    = (u16*)(ws + 2 * S);
    u16* NbB   = (u16*)(ws + 2 * S) + S;
    u16* FFb16 = (u16*)(ws + 3 * S);
    u16* RopeB = FFb16;
    u16* embB  = FFb16;
    u16* RB    = (u16*)(ws + 4 * S);
    u16* projwB = (u16*)(ws + 5 * S);
    u16* iwB  = projwB + 512 * 1280;
    u16* owB  = iwB + (size_t)NL_ * 3 * D_ * D_;
    u16* w1B  = owB + (size_t)NL_ * D_ * D_;
    u16* w2B  = w1B + (size_t)NL_ * FF_ * D_;
    u16* h1wB = w2B + (size_t)NL_ * D_ * FF_;
    float* CT = ws + 5 * S + 6651904;
    float* ST = CT + L_ * DH_;
    float* GC = ST + L_ * DH_;
    float* GP = GC + B_ * D_;
    float* Pp = GP + B_ * 128;            // [B*16, 512] partials
    float* Mp = Pp + (size_t)B_ * 16 * D_;
    float* QBS = Mp + B_ * 16;            // [NL,1024] scaled q/k bias
    float* Hb = Rf;

    const int MT = 128;
    const dim3 blk(256);
    const int lnGrid = (BL_ + 3) / 4;

    cast_k<<<(BL_ * E_ / 8 + 255) / 256, blk, 0, stream>>>(emb, embB, BL_ * E_ / 8);
    cast_k<<<(512 * 1280 / 8 + 255) / 256, blk, 0, stream>>>(proj_w, projwB, 512 * 1280 / 8);
    castq_k<<<(NL_ * 3 * D_ * D_ / 8 + 255) / 256, blk, 0, stream>>>(in_w, iwB, NL_ * 3 * D_ * D_ / 8);
    qbias_k<<<(NL_ * 1024 + 255) / 256, blk, 0, stream>>>(in_b, QBS);
    cast_k<<<(NL_ * D_ * D_ / 8 + 255) / 256, blk, 0, stream>>>(out_w, owB, NL_ * D_ * D_ / 8);
    cast_k<<<(NL_ * FF_ * D_ / 8 + 255) / 256, blk, 0, stream>>>(w1, w1B, NL_ * FF_ * D_ / 8);
    cast_k<<<(NL_ * D_ * FF_ / 8 + 255) / 256, blk, 0, stream>>>(w2, w2B, NL_ * D_ * FF_ / 8);
    h1cast_k<<<(128 * 512 / 8 + 255) / 256, blk, 0, stream>>>(h1_w, h1wB);
    tables_k<<<(L_ * DH_ + 255) / 256, blk, 0, stream>>>(CT, ST);

    mgemm_k<false,false,false,false><<<MT * (D_ / 128), blk, 0, stream>>>(
        embB, projwB, proj_b, nullptr, Rf, BL_, D_, E_);
    ln_k<D_,false,true,false><<<lnGrid, blk, 0, stream>>>(Rf, proj_ln_s, proj_ln_b, X, BL_);

    for (int i = 0; i < NL_; i++) {
        const u16* iw = iwB + (size_t)i * 3 * D_ * D_;
        const float* ib = in_b + (size_t)i * 3 * D_;
        ln_k<D_,false,true,true><<<lnGrid, blk, 0, stream>>>(X, ln1_s + i * D_, ln1_b + i * D_, NbB, BL_);
        mgemm_k<false,false,true,false><<<MT * 4, blk, 0, stream>>>(
            NbB, iw + 2 * D_ * D_, ib + 2 * D_, nullptr, VB, BL_, D_, D_);
        rope_k<<<(BL_ * D_ / 8 + 255) / 256, blk, 0, stream>>>(NbB, CT, ST, RopeB);
        // fused q+k projection (wq pre-scaled by QSC_, bias = QBS[i])
        mgemm_k<false,false,true,false><<<MT * 8, blk, 0, stream>>>(
            RopeB, iw, QBS + (size_t)i * 1024, nullptr, QKB, BL_, 1024, D_);
        attn_k<<<B_ * H_ * 16, blk, 0, stream>>>(QKB, VB, mask, RB);
        mgemm_k<false,true,true,false><<<MT * 4, blk, 0, stream>>>(
            RB, owB + (size_t)i * D_ * D_, out_b + i * D_, X, X, BL_, D_, D_);
        ln_k<D_,false,true,true><<<lnGrid, blk, 0, stream>>>(X, ln2_s + i * D_, ln2_b + i * D_, NbB, BL_);
        mgemm_k<true,false,true,false><<<MT * 16, blk, 0, stream>>>(
            NbB, w1B + (size_t)i * FF_ * D_, b1 + i * FF_, nullptr, FFb16, BL_, FF_, D_);
        mgemm_k<false,true,true,false><<<MT * 4, blk, 0, stream>>>(
            FFb16, w2B + (size_t)i * D_ * FF_, b2 + i * D_, X, X, BL_, D_, FF_);
    }

    pool1_k<<<dim3(B_, 16), dim3(512), 0, stream>>>(X, mask, Pp, Mp);
    pool2_k<<<B_, dim3(512), 0, stream>>>(Pp, Mp, GC);
    gpart_k<<<(B_ * 128) / 4, blk, 0, stream>>>(GC, h1_w, h1_b, GP);
    mgemm_k<false,false,false,true><<<MT * 1, blk, 0, stream>>>(
        X, h1wB, GP, nullptr, Hb, BL_, 128, D_);
    ln_k<128,true,false,false><<<lnGrid, blk, 0, stream>>>(Hb, hln_s, hln_b, Hb, BL_);
    logits_k<<<lnGrid, blk, 0, stream>>>(Hb, h2_w, h2_b, out, BL_);
}

// Round 11
// 1450.355 us; speedup vs baseline: 1.0347x; 1.0238x over previous
//
#include <hip/hip_runtime.h>
#include <cstdint>
#include <cstddef>

// ---------------- problem constants ----------------
#define B_   16
#define L_   1022
#define E_   1280
#define D_   512
#define H_   8
#define FF_  2048
#define NL_  4
#define DH_  64
#define BL_  (B_*L_)      // 16352
#define EPS_ 1e-5f
#define QSC_ 0.18033688011112042f   // 0.125 * log2(e)

typedef unsigned short u16;
typedef unsigned int   u32;
typedef unsigned long long u64;
typedef float f32x4 __attribute__((ext_vector_type(4)));
typedef short s16x8 __attribute__((ext_vector_type(8)));
typedef u32 u32x4 __attribute__((ext_vector_type(4)));

__device__ __forceinline__ u16 f2bf(float f) {
    u32 u = __builtin_bit_cast(u32, f);
    u += 0x7fffu + ((u >> 16) & 1u);
    return (u16)(u >> 16);
}
__device__ __forceinline__ float bf2f(u16 u) {
    return __builtin_bit_cast(float, (u32)u << 16);
}
__device__ __forceinline__ u32 pack2bf(float a, float b) {
    return (u32)f2bf(a) | ((u32)f2bf(b) << 16);
}

// ======================================================================
// fp32 -> bf16 cast, 8 elems/thread
// ======================================================================
__global__ __launch_bounds__(256)
void cast_k(const float* __restrict__ src, u16* __restrict__ dst, int n8) {
    int t = blockIdx.x * 256 + threadIdx.x;
    if (t >= n8) return;
    const float* s = src + (size_t)t * 8;
    float4 a = *(const float4*)(s);
    float4 b = *(const float4*)(s + 4);
    s16x8 o;
    o[0] = (short)f2bf(a.x); o[1] = (short)f2bf(a.y);
    o[2] = (short)f2bf(a.z); o[3] = (short)f2bf(a.w);
    o[4] = (short)f2bf(b.x); o[5] = (short)f2bf(b.y);
    o[6] = (short)f2bf(b.z); o[7] = (short)f2bf(b.w);
    *(s16x8*)(dst + (size_t)t * 8) = o;
}

// in_w cast with wq rows (row%1536 < 512) pre-scaled by QSC_ (exp2-domain
// softmax: folds 1/sqrt(DH) * log2(e) into the Q projection)
__global__ __launch_bounds__(256)
void castq_k(const float* __restrict__ src, u16* __restrict__ dst, int n8) {
    int t = blockIdx.x * 256 + threadIdx.x;
    if (t >= n8) return;
    int row = t >> 6;                  // 512 cols / 8 per chunk
    float sc = (row % 1536) < 512 ? QSC_ : 1.0f;
    const float* s = src + (size_t)t * 8;
    float4 a = *(const float4*)(s);
    float4 b = *(const float4*)(s + 4);
    s16x8 o;
    o[0] = (short)f2bf(a.x * sc); o[1] = (short)f2bf(a.y * sc);
    o[2] = (short)f2bf(a.z * sc); o[3] = (short)f2bf(a.w * sc);
    o[4] = (short)f2bf(b.x * sc); o[5] = (short)f2bf(b.y * sc);
    o[6] = (short)f2bf(b.z * sc); o[7] = (short)f2bf(b.w * sc);
    *(s16x8*)(dst + (size_t)t * 8) = o;
}

// scaled q/k bias: qbs[i][j] = in_b[i*1536+j] * (j<512?QSC:1)
__global__ __launch_bounds__(256)
void qbias_k(const float* __restrict__ ib, float* __restrict__ qbs) {
    int t = blockIdx.x * 256 + threadIdx.x;
    if (t >= NL_ * 1024) return;
    int i = t >> 10, j = t & 1023;
    float sc = j < 512 ? QSC_ : 1.0f;
    qbs[t] = ib[i * 1536 + j] * sc;
}

// h1_w left half [128, 0:512] (row stride 1024) -> packed bf16 [128,512]
__global__ __launch_bounds__(256)
void h1cast_k(const float* __restrict__ src, u16* __restrict__ dst) {
    int t = blockIdx.x * 256 + threadIdx.x;
    if (t >= 128 * 512 / 8) return;
    int row = t >> 6, c8 = (t & 63) << 3;
    const float* s = src + (size_t)row * 1024 + c8;
    float4 a = *(const float4*)(s);
    float4 b = *(const float4*)(s + 4);
    s16x8 o;
    o[0] = (short)f2bf(a.x); o[1] = (short)f2bf(a.y);
    o[2] = (short)f2bf(a.z); o[3] = (short)f2bf(a.w);
    o[4] = (short)f2bf(b.x); o[5] = (short)f2bf(b.y);
    o[6] = (short)f2bf(b.z); o[7] = (short)f2bf(b.w);
    *(s16x8*)(dst + (size_t)row * 512 + c8) = o;
}

// ======================================================================
// RoPE cos/sin tables
// ======================================================================
__global__ void tables_k(float* __restrict__ ct, float* __restrict__ st) {
    int idx = blockIdx.x * blockDim.x + threadIdx.x;
    if (idx >= L_ * DH_) return;
    int l = idx / DH_;
    int d = idx % DH_;
    int j = d & 31;
    float invf = powf(10000.0f, -(float)(2 * j) / (float)DH_);
    float ang = (float)l * invf;
    ct[idx] = cosf(ang);
    st[idx] = sinf(ang);
}

// ======================================================================
// bf16 MFMA GEMM (reg-staged): C = act(A @ W^T + bias)(+resid bf16)
// 128x128 tile, BK=64, 256 threads (4 waves 2x2), 4x4 16x16 frags/wave.
// ======================================================================
template<bool RELU, bool RESID, bool OUTBF, bool ROWBIAS>
__global__ __launch_bounds__(256)
void mgemm_k(const u16* __restrict__ A, const u16* __restrict__ W,
             const float* __restrict__ bias, const u16* __restrict__ resid,
             void* __restrict__ Cout, int M, int N, int K)
{
    constexpr int LDT = 72;               // padded LDS row stride (bf16)
    __shared__ u16 As[128 * LDT];
    __shared__ u16 Ws[128 * LDT];
    const int nt = N >> 7;
    const int bx = blockIdx.x % nt;
    const int by = blockIdx.x / nt;
    const int m0 = by << 7, n0 = bx << 7;
    const int tid = threadIdx.x;
    const int lane = tid & 63, wid = tid >> 6;
    const int wr = wid >> 1, wc = wid & 1;
    const int lr = lane & 15, lk = lane >> 4;

    f32x4 acc[4][4];
#pragma unroll
    for (int m = 0; m < 4; m++)
#pragma unroll
        for (int n = 0; n < 4; n++) acc[m][n] = (f32x4)0.0f;

    for (int k0 = 0; k0 < K; k0 += 64) {
        s16x8 va[4], vw[4];
#pragma unroll
        for (int u = 0; u < 4; u++) {
            int ch = tid + (u << 8);          // 16B chunk id, 0..1023
            int r = ch >> 3, c8 = (ch & 7) << 3;
            int ar = m0 + r; if (ar >= M) ar = M - 1;
            va[u] = *(const s16x8*)(A + (size_t)ar * K + k0 + c8);
            vw[u] = *(const s16x8*)(W + (size_t)(n0 + r) * K + k0 + c8);
        }
        __syncthreads();   // previous iteration's LDS reads complete
#pragma unroll
        for (int u = 0; u < 4; u++) {
            int ch = tid + (u << 8);
            int r = ch >> 3, c8 = (ch & 7) << 3;
            *(s16x8*)&As[r * LDT + c8] = va[u];
            *(s16x8*)&Ws[r * LDT + c8] = vw[u];
        }
        __syncthreads();   // tiles staged
#pragma unroll
        for (int kk = 0; kk < 2; kk++) {
            s16x8 af[4], bf[4];
#pragma unroll
            for (int m = 0; m < 4; m++)
                af[m] = *(const s16x8*)&As[(wr * 64 + m * 16 + lr) * LDT + kk * 32 + lk * 8];
#pragma unroll
            for (int n = 0; n < 4; n++)
                bf[n] = *(const s16x8*)&Ws[(wc * 64 + n * 16 + lr) * LDT + kk * 32 + lk * 8];
#pragma unroll
            for (int m = 0; m < 4; m++)
#pragma unroll
                for (int n = 0; n < 4; n++)
                    acc[m][n] = __builtin_amdgcn_mfma_f32_16x16x32_bf16(
                        af[m], bf[n], acc[m][n], 0, 0, 0);
        }
    }

    float bv[4];
    if constexpr (!ROWBIAS) {
#pragma unroll
        for (int n = 0; n < 4; n++) bv[n] = bias[n0 + wc * 64 + n * 16 + lr];
    }
#pragma unroll
    for (int m = 0; m < 4; m++) {
#pragma unroll
        for (int j = 0; j < 4; j++) {
            int row = m0 + wr * 64 + m * 16 + lk * 4 + j;
            if (row >= M) continue;
            const float* rb = nullptr;
            if constexpr (ROWBIAS) rb = bias + (size_t)(row / L_) * N;
#pragma unroll
            for (int n = 0; n < 4; n++) {
                int col = n0 + wc * 64 + n * 16 + lr;
                float c = acc[m][n][j];
                if constexpr (ROWBIAS) c += rb[col];
                else                   c += bv[n];
                if constexpr (RELU) c = fmaxf(c, 0.0f);
                if constexpr (RESID) c += bf2f(resid[(size_t)row * N + col]);
                if constexpr (OUTBF) ((u16*)Cout)[(size_t)row * N + col] = f2bf(c);
                else                 ((float*)Cout)[(size_t)row * N + col] = c;
            }
        }
    }
}

// ======================================================================
// LayerNorm: one wave per row; RELU / bf16-out / bf16-in options.
// ======================================================================
template<int DD, bool RELU, bool OUTBF, bool INBF>
__global__ __launch_bounds__(256)
void ln_k(const void* __restrict__ xin, const float* __restrict__ s,
          const float* __restrict__ bb, void* __restrict__ out, int M)
{
    const int lane = threadIdx.x & 63;
    const int row = (blockIdx.x << 2) + (threadIdx.x >> 6);
    if (row >= M) return;
    constexpr int NV = DD / 64;
    float v[NV];
    if constexpr (INBF) {
        const u16* xr = (const u16*)xin + (size_t)row * DD;
        if constexpr (NV == 8) {
            s16x8 t = *(const s16x8*)(xr + lane * 8);
#pragma unroll
            for (int e = 0; e < 8; e++) v[e] = bf2f((u16)t[e]);
        } else {
            v[0] = bf2f(xr[lane * 2]); v[1] = bf2f(xr[lane * 2 + 1]);
        }
    } else {
        const float* xr = (const float*)xin + (size_t)row * DD;
        if constexpr (NV == 8) {
            *(float4*)(v)     = *(const float4*)(xr + lane * 8);
            *(float4*)(v + 4) = *(const float4*)(xr + lane * 8 + 4);
        } else {
            float2 t = *(const float2*)(xr + lane * 2);
            v[0] = t.x; v[1] = t.y;
        }
    }
    float sum = 0.f, sq = 0.f;
#pragma unroll
    for (int e = 0; e < NV; e++) { sum += v[e]; sq += v[e] * v[e]; }
#pragma unroll
    for (int msk = 1; msk < 64; msk <<= 1) {
        sum += __shfl_xor(sum, msk);
        sq  += __shfl_xor(sq, msk);
    }
    const float mean = sum * (1.0f / DD);
    const float var  = sq * (1.0f / DD) - mean * mean;
    const float rstd = rsqrtf(var + EPS_);
#pragma unroll
    for (int e = 0; e < NV; e++) {
        int d = lane * NV + e;
        float r = (v[e] - mean) * rstd * s[d] + bb[d];
        if constexpr (RELU) r = fmaxf(r, 0.0f);
        v[e] = r;
    }
    if constexpr (OUTBF) {
        u16* orow = (u16*)out + (size_t)row * DD;
        if constexpr (NV == 8) {
            s16x8 o;
#pragma unroll
            for (int e = 0; e < 8; e++) o[e] = (short)f2bf(v[e]);
            *(s16x8*)(orow + lane * 8) = o;
        } else {
            orow[lane * 2] = f2bf(v[0]); orow[lane * 2 + 1] = f2bf(v[1]);
        }
    } else {
        float* orow = (float*)out + (size_t)row * DD;
        if constexpr (NV == 8) {
            *(float4*)(orow + lane * 8)     = *(float4*)(v);
            *(float4*)(orow + lane * 8 + 4) = *(float4*)(v + 4);
        } else {
            float2 t; t.x = v[0]; t.y = v[1];
            *(float2*)(orow + lane * 2) = t;
        }
    }
}

// ======================================================================
// RoPE on bf16 [BL,512] -> bf16, 8 elems/thread
// ======================================================================
__global__ __launch_bounds__(256)
void rope_k(const u16* __restrict__ n, const float* __restrict__ ct,
            const float* __restrict__ st, u16* __restrict__ r)
{
    int t = blockIdx.x * 256 + threadIdx.x;
    if (t >= BL_ * D_ / 8) return;
    int idx = t << 3;
    int l = (idx / D_) % L_;
    int d = idx & (D_ - 1);
    int dd = d & 63;
    s16x8 xv = *(const s16x8*)(n + idx);
    int pidx; float sgn;
    if (dd < 32) { pidx = idx + 32; sgn = -1.0f; }
    else         { pidx = idx - 32; sgn =  1.0f; }
    s16x8 pv = *(const s16x8*)(n + pidx);
    float4 c0 = *(const float4*)(ct + l * DH_ + dd);
    float4 c1 = *(const float4*)(ct + l * DH_ + dd + 4);
    float4 s0 = *(const float4*)(st + l * DH_ + dd);
    float4 s1 = *(const float4*)(st + l * DH_ + dd + 4);
    float cc[8] = {c0.x,c0.y,c0.z,c0.w,c1.x,c1.y,c1.z,c1.w};
    float ss[8] = {s0.x,s0.y,s0.z,s0.w,s1.x,s1.y,s1.z,s1.w};
    s16x8 o;
#pragma unroll
    for (int e = 0; e < 8; e++) {
        float xf = bf2f((u16)xv[e]);
        float pf = bf2f((u16)pv[e]);
        o[e] = (short)f2bf(xf * cc[e] + sgn * pf * ss[e]);
    }
    *(s16x8*)(r + idx) = o;
}

// ======================================================================
// MFMA flash attention, swapped-operand (S^T = K Q^T), in-register
// softmax in exp2 domain (Q pre-scaled by 0.125*log2e at weight cast).
// r8-proven two-barrier structure, unconditional rescale (64-VGPR config).
// ======================================================================
__global__ __launch_bounds__(256)
void attn_k(const u16* __restrict__ qk, const u16* __restrict__ v,
            const float* __restrict__ mask, u16* __restrict__ o)
{
    constexpr int LDA = 68;
    __shared__ u16 Kt[64 * LDA];
    __shared__ u16 Vt[64 * LDA];
    const int bh = blockIdx.x >> 4, qt = blockIdx.x & 15;
    const int b = bh >> 3, h = bh & 7;
    const int tid = threadIdx.x;
    const int lane = tid & 63, w = tid >> 6;
    const int lr = lane & 15, lg = lane >> 4;
    const size_t basebl = (size_t)b * L_;

    // Q B-frags: lane's q-row = qt*64 + w*16 + lr (pre-scaled weights)
    const int qrow = qt * 64 + w * 16 + lr;
    const int qc = qrow < L_ ? qrow : L_ - 1;
    s16x8 bq[2];
#pragma unroll
    for (int kk = 0; kk < 2; kk++)
        bq[kk] = *(const s16x8*)(qk + (basebl + qc) * 1024 + h * DH_ + kk * 32 + lg * 8);

    f32x4 oacc[4];            // O^T: col q=lr, rows d = 16*n2 + 4*lg + j
#pragma unroll
    for (int n = 0; n < 4; n++) oacc[n] = (f32x4)0.0f;
    float m_run = -1e30f, l_run = 0.f;

    const int st_key = tid >> 3;          // 0..31 (+32 for u=1)
    const int st_d8 = (tid & 7) << 3;
    const int src0 = lr + ((lane & 16) << 1);   // lr + 32*(lg&1)
    const int src1 = src0 + 16;
    const bool ahi = (lg >> 1) != 0;

    for (int kt = 0; kt < 16; kt++) {
        __syncthreads();          // all waves done reading prev Kt/Vt
#pragma unroll
        for (int u = 0; u < 2; u++) {
            int key = st_key + u * 32;
            int gk = kt * 64 + key; if (gk >= L_) gk = L_ - 1;
            s16x8 kv = *(const s16x8*)(qk + (basebl + gk) * 1024 + 512 + h * DH_ + st_d8);
            s16x8 vv = *(const s16x8*)(v  + (basebl + gk) * D_ + h * DH_ + st_d8);
            *(s16x8*)&Kt[key * LDA + st_d8] = kv;
#pragma unroll
            for (int e = 0; e < 8; e++) Vt[(st_d8 + e) * LDA + key] = (u16)vv[e];
        }
        __syncthreads();

        // key validity via one ballot
        int gkey = kt * 64 + lane;
        bool vb = (gkey < L_) && (mask[basebl + gkey] > 0.0f);
        u64 vm = __ballot(vb);

        // S^T = K Q^T (exp2 domain)
        f32x4 sacc[4];
#pragma unroll
        for (int n = 0; n < 4; n++) {
            sacc[n] = (f32x4)0.0f;
#pragma unroll
            for (int kk = 0; kk < 2; kk++) {
                s16x8 ak = *(const s16x8*)&Kt[(n * 16 + lr) * LDA + kk * 32 + lg * 8];
                sacc[n] = __builtin_amdgcn_mfma_f32_16x16x32_bf16(ak, bq[kk], sacc[n], 0, 0, 0);
            }
        }

        // masked in-register max (lane holds 16 S of one q-row)
        float p[4][4];
        float tm = -1e30f;
#pragma unroll
        for (int n = 0; n < 4; n++)
#pragma unroll
            for (int j = 0; j < 4; j++) {
                int kl = 16 * n + 4 * lg + j;
                float s = ((vm >> kl) & 1ull) ? sacc[n][j] : -1e30f;
                p[n][j] = s;
                tm = fmaxf(tm, s);
            }
        tm = fmaxf(tm, __shfl_xor(tm, 16));
        tm = fmaxf(tm, __shfl_xor(tm, 32));
        float nm = fmaxf(m_run, tm);
        float corr = exp2f(m_run - nm);
        m_run = nm;
        float ts = 0.f;
#pragma unroll
        for (int n = 0; n < 4; n++)
#pragma unroll
            for (int j = 0; j < 4; j++) {
                p[n][j] = exp2f(p[n][j] - nm);
                ts += p[n][j];
            }
        ts += __shfl_xor(ts, 16);
        ts += __shfl_xor(ts, 32);
        l_run = l_run * corr + ts;
#pragma unroll
        for (int n = 0; n < 4; n++) oacc[n] *= corr;

        // pack P -> bf16 pairs; redistribute to PV B-frag layout
        u32 pk[4][2];
#pragma unroll
        for (int n = 0; n < 4; n++) {
            pk[n][0] = pack2bf(p[n][0], p[n][1]);
            pk[n][1] = pack2bf(p[n][2], p[n][3]);
        }
        u32 r0[4][2], r1[4][2];
#pragma unroll
        for (int n = 0; n < 4; n++)
#pragma unroll
            for (int i = 0; i < 2; i++) {
                r0[n][i] = (u32)__shfl((int)pk[n][i], src0);
                r1[n][i] = (u32)__shfl((int)pk[n][i], src1);
            }
#pragma unroll
        for (int kk = 0; kk < 2; kk++) {
            u32x4 bw;
            bw[0] = ahi ? r0[2 * kk + 1][0] : r0[2 * kk][0];
            bw[1] = ahi ? r0[2 * kk + 1][1] : r0[2 * kk][1];
            bw[2] = ahi ? r1[2 * kk + 1][0] : r1[2 * kk][0];
            bw[3] = ahi ? r1[2 * kk + 1][1] : r1[2 * kk][1];
            s16x8 bp = __builtin_bit_cast(s16x8, bw);
#pragma unroll
            for (int n2 = 0; n2 < 4; n2++) {
                s16x8 av = *(const s16x8*)&Vt[(n2 * 16 + lr) * LDA + kk * 32 + lg * 8];
                oacc[n2] = __builtin_amdgcn_mfma_f32_16x16x32_bf16(av, bp, oacc[n2], 0, 0, 0);
            }
        }
    }

    // epilogue: normalize, transpose via reused Kt (wave-private 16 rows)
    __syncthreads();   // all waves done with Kt/Vt MFMA reads
    u16* Ol = &Kt[w * 16 * LDA];
    float inv = 1.0f / l_run;
#pragma unroll
    for (int n = 0; n < 4; n++)
#pragma unroll
        for (int j = 0; j < 4; j++)
            Ol[lr * LDA + 16 * n + 4 * lg + j] = f2bf(oacc[n][j] * inv);
    int orow = lane >> 2, oc = (lane & 3) * 16;
    int qg = qt * 64 + w * 16 + orow;
    if (qg < L_) {
        s16x8 o0 = *(const s16x8*)&Ol[orow * LDA + oc];
        s16x8 o1 = *(const s16x8*)&Ol[orow * LDA + oc + 8];
        *(s16x8*)(o + (basebl + qg) * D_ + h * DH_ + oc) = o0;
        *(s16x8*)(o + (basebl + qg) * D_ + h * DH_ + oc + 8) = o1;
    }
}

// ======================================================================
// masked mean pool, two-stage (X bf16).
// ======================================================================
__global__ __launch_bounds__(512)
void pool1_k(const u16* __restrict__ x, const float* __restrict__ mask,
             float* __restrict__ pp, float* __restrict__ mp)
{
    const int b = blockIdx.x, sp = blockIdx.y;
    const int d = threadIdx.x;
    const int l0 = sp * 64;
    float acc = 0.f;
    for (int l = l0; l < l0 + 64 && l < L_; l++)
        acc += bf2f(x[((size_t)b * L_ + l) * D_ + d]) * mask[b * L_ + l];
    pp[((size_t)b * 16 + sp) * D_ + d] = acc;
    if (d == 0) {
        float ms = 0.f;
        for (int l = l0; l < l0 + 64 && l < L_; l++) ms += mask[b * L_ + l];
        mp[b * 16 + sp] = ms;
    }
}

__global__ __launch_bounds__(512)
void pool2_k(const float* __restrict__ pp, const float* __restrict__ mp,
             float* __restrict__ g)
{
    const int b = blockIdx.x;
    const int d = threadIdx.x;
    float acc = 0.f, ms = 0.f;
#pragma unroll
    for (int sp = 0; sp < 16; sp++) {
        acc += pp[((size_t)b * 16 + sp) * D_ + d];
        ms += mp[b * 16 + sp];
    }
    g[b * D_ + d] = acc / ms;
}

// ======================================================================
// gpart[b][j] = h1_b[j] + dot(gctx[b], h1_w[j, 512:1024])  (fp32)
// ======================================================================
__global__ __launch_bounds__(256)
void gpart_k(const float* __restrict__ g, const float* __restrict__ h1w,
             const float* __restrict__ h1b, float* __restrict__ gp)
{
    const int lane = threadIdx.x & 63;
    const int gid = (blockIdx.x << 2) + (threadIdx.x >> 6);
    const int b = gid >> 7, j = gid & 127;
    const float* wr = h1w + (size_t)j * (2 * D_) + D_;
    const float* gr = g + b * D_;
    float4 a0 = *(const float4*)(gr + lane * 8);
    float4 a1 = *(const float4*)(gr + lane * 8 + 4);
    float4 w0 = *(const float4*)(wr + lane * 8);
    float4 w1v = *(const float4*)(wr + lane * 8 + 4);
    float acc = a0.x * w0.x + a0.y * w0.y + a0.z * w0.z + a0.w * w0.w
              + a1.x * w1v.x + a1.y * w1v.y + a1.z * w1v.z + a1.w * w1v.w;
#pragma unroll
    for (int msk = 1; msk < 64; msk <<= 1) acc += __shfl_xor(acc, msk);
    if (lane == 0) gp[b * 128 + j] = acc + h1b[j];
}

// ======================================================================
// logits[m] = h2_b + dot(h[m,0:128], h2_w)
// ======================================================================
__global__ __launch_bounds__(256)
void logits_k(const float* __restrict__ h, const float* __restrict__ w,
              const float* __restrict__ bsc, float* __restrict__ out, int M)
{
    const int lane = threadIdx.x & 63;
    const int row = (blockIdx.x << 2) + (threadIdx.x >> 6);
    if (row >= M) return;
    float2 hv = *(const float2*)(h + (size_t)row * 128 + lane * 2);
    float2 wv = *(const float2*)(w + lane * 2);
    float acc = hv.x * wv.x + hv.y * wv.y;
#pragma unroll
    for (int msk = 1; msk < 64; msk <<= 1) acc += __shfl_xor(acc, msk);
    if (lane == 0) out[row] = acc + bsc[0];
}

// ======================================================================
// host orchestration
// ======================================================================
extern "C" void kernel_launch(void* const* d_in, const int* in_sizes, int n_in,
                              void* d_out, int out_size, void* d_ws, size_t ws_size,
                              hipStream_t stream)
{
    const float* emb       = (const float*)d_in[0];
    const float* mask      = (const float*)d_in[1];
    const float* proj_w    = (const float*)d_in[3];
    const float* proj_b    = (const float*)d_in[4];
    const float* proj_ln_s = (const float*)d_in[5];
    const float* proj_ln_b = (const float*)d_in[6];
    const float* ln1_s     = (const float*)d_in[7];
    const float* ln1_b     = (const float*)d_in[8];
    const float* in_w      = (const float*)d_in[9];
    const float* in_b      = (const float*)d_in[10];
    const float* out_w     = (const float*)d_in[11];
    const float* out_b     = (const float*)d_in[12];
    const float* ln2_s     = (const float*)d_in[13];
    const float* ln2_b     = (const float*)d_in[14];
    const float* w1        = (const float*)d_in[15];
    const float* b1        = (const float*)d_in[16];
    const float* w2        = (const float*)d_in[17];
    const float* b2        = (const float*)d_in[18];
    const float* h1_w      = (const float*)d_in[19];
    const float* h1_b      = (const float*)d_in[20];
    const float* hln_s     = (const float*)d_in[21];
    const float* hln_b     = (const float*)d_in[22];
    const float* h2_w      = (const float*)d_in[23];
    const float* h2_b      = (const float*)d_in[24];
    float* out = (float*)d_out;

    // Workspace map (S = BL*D floats):
    //   [0,0.5S)   X bf16 residual stream [BL,512]
    //   [S,2S)     Rf fp32 (proj-out, head Hb) / QKB bf16 [BL,1024] (disjoint)
    //   [2S,2.5S)  VB bf16
    //   [2.5S,3S)  NbB bf16
    //   [3S,5S)    FFb16 bf16 [BL,2048]; aliases embB, RopeB, RB (disjoint)
    //   [5S,...)   bf16 weights, CT/ST/GC/GP/Pp/Mp/QBS
    float* ws = (float*)d_ws;
    const size_t S = (size_t)BL_ * D_;
    u16* X = (u16*)ws;                    // bf16 residual
    float* Rf = ws + S;
    u16* QKB   = (u16*)(ws + S);
    u16* VB    = (u16*)(ws + 2 * S);
    u16* NbB   = (u16*)(ws + 2 * S) + S;
    u16* FFb16 = (u16*)(ws + 3 * S);
    u16* RopeB = FFb16;
    u16* embB  = FFb16;
    u16* RB    = (u16*)(ws + 4 * S);
    u16* projwB = (u16*)(ws + 5 * S);
    u16* iwB  = projwB + 512 * 1280;
    u16* owB  = iwB + (size_t)NL_ * 3 * D_ * D_;
    u16* w1B  = owB + (size_t)NL_ * D_ * D_;
    u16* w2B  = w1B + (size_t)NL_ * FF_ * D_;
    u16* h1wB = w2B + (size_t)NL_ * D_ * FF_;
    float* CT = ws + 5 * S + 6651904;
    float* ST = CT + L_ * DH_;
    float* GC = ST + L_ * DH_;
    float* GP = GC + B_ * D_;
    float* Pp = GP + B_ * 128;            // [B*16, 512] partials
    float* Mp = Pp + (size_t)B_ * 16 * D_;
    float* QBS = Mp + B_ * 16;            // [NL,1024] scaled q/k bias
    float* Hb = Rf;

    const int MT = 128;
    const dim3 blk(256);
    const int lnGrid = (BL_ + 3) / 4;

    cast_k<<<(BL_ * E_ / 8 + 255) / 256, blk, 0, stream>>>(emb, embB, BL_ * E_ / 8);
    cast_k<<<(512 * 1280 / 8 + 255) / 256, blk, 0, stream>>>(proj_w, projwB, 512 * 1280 / 8);
    castq_k<<<(NL_ * 3 * D_ * D_ / 8 + 255) / 256, blk, 0, stream>>>(in_w, iwB, NL_ * 3 * D_ * D_ / 8);
    qbias_k<<<(NL_ * 1024 + 255) / 256, blk, 0, stream>>>(in_b, QBS);
    cast_k<<<(NL_ * D_ * D_ / 8 + 255) / 256, blk, 0, stream>>>(out_w, owB, NL_ * D_ * D_ / 8);
    cast_k<<<(NL_ * FF_ * D_ / 8 + 255) / 256, blk, 0, stream>>>(w1, w1B, NL_ * FF_ * D_ / 8);
    cast_k<<<(NL_ * D_ * FF_ / 8 + 255) / 256, blk, 0, stream>>>(w2, w2B, NL_ * D_ * FF_ / 8);
    h1cast_k<<<(128 * 512 / 8 + 255) / 256, blk, 0, stream>>>(h1_w, h1wB);
    tables_k<<<(L_ * DH_ + 255) / 256, blk, 0, stream>>>(CT, ST);

    mgemm_k<false,false,false,false><<<MT * (D_ / 128), blk, 0, stream>>>(
        embB, projwB, proj_b, nullptr, Rf, BL_, D_, E_);
    ln_k<D_,false,true,false><<<lnGrid, blk, 0, stream>>>(Rf, proj_ln_s, proj_ln_b, X, BL_);

    for (int i = 0; i < NL_; i++) {
        const u16* iw = iwB + (size_t)i * 3 * D_ * D_;
        const float* ib = in_b + (size_t)i * 3 * D_;
        ln_k<D_,false,true,true><<<lnGrid, blk, 0, stream>>>(X, ln1_s + i * D_, ln1_b + i * D_, NbB, BL_);
        mgemm_k<false,false,true,false><<<MT * 4, blk, 0, stream>>>(
            NbB, iw + 2 * D_ * D_, ib + 2 * D_, nullptr, VB, BL_, D_, D_);
        rope_k<<<(BL_ * D_ / 8 + 255) / 256, blk, 0, stream>>>(NbB, CT, ST, RopeB);
        // fused q+k projection (wq pre-scaled by QSC_, bias = QBS[i])
        mgemm_k<false,false,true,false><<<MT * 8, blk, 0, stream>>>(
            RopeB, iw, QBS + (size_t)i * 1024, nullptr, QKB, BL_, 1024, D_);
        attn_k<<<B_ * H_ * 16, blk, 0, stream>>>(QKB, VB, mask, RB);
        mgemm_k<false,true,true,false><<<MT * 4, blk, 0, stream>>>(
            RB, owB + (size_t)i * D_ * D_, out_b + i * D_, X, X, BL_, D_, D_);
        ln_k<D_,false,true,true><<<lnGrid, blk, 0, stream>>>(X, ln2_s + i * D_, ln2_b + i * D_, NbB, BL_);
        mgemm_k<true,false,true,false><<<MT * 16, blk, 0, stream>>>(
            NbB, w1B + (size_t)i * FF_ * D_, b1 + i * FF_, nullptr, FFb16, BL_, FF_, D_);
        mgemm_k<false,true,true,false><<<MT * 4, blk, 0, stream>>>(
            FFb16, w2B + (size_t)i * D_ * FF_, b2 + i * D_, X, X, BL_, D_, FF_);
    }

    pool1_k<<<dim3(B_, 16), dim3(512), 0, stream>>>(X, mask, Pp, Mp);
    pool2_k<<<B_, dim3(512), 0, stream>>>(Pp, Mp, GC);
    gpart_k<<<(B_ * 128) / 4, blk, 0, stream>>>(GC, h1_w, h1_b, GP);
    mgemm_k<false,false,false,true><<<MT * 1, blk, 0, stream>>>(
        X, h1wB, GP, nullptr, Hb, BL_, 128, D_);
    ln_k<128,true,false,false><<<lnGrid, blk, 0, stream>>>(Hb, hln_s, hln_b, Hb, BL_);
    logits_k<<<lnGrid, blk, 0, stream>>>(Hb, h2_w, h2_b, out, BL_);
}

// Round 12
// 1412.732 us; speedup vs baseline: 1.0623x; 1.0266x over previous
//
#include <hip/hip_runtime.h>
#include <cstdint>
#include <cstddef>

// ---------------- problem constants ----------------
#define B_   16
#define L_   1022
#define E_   1280
#define D_   512
#define H_   8
#define FF_  2048
#define NL_  4
#define DH_  64
#define BL_  (B_*L_)      // 16352
#define EPS_ 1e-5f
#define QSC_ 0.18033688011112042f   // 0.125 * log2(e)

typedef unsigned short u16;
typedef unsigned int   u32;
typedef unsigned long long u64;
typedef float f32x4 __attribute__((ext_vector_type(4)));
typedef short s16x8 __attribute__((ext_vector_type(8)));
typedef u32 u32x4 __attribute__((ext_vector_type(4)));

__device__ __forceinline__ u16 f2bf(float f) {
    u32 u = __builtin_bit_cast(u32, f);
    u += 0x7fffu + ((u >> 16) & 1u);
    return (u16)(u >> 16);
}
__device__ __forceinline__ float bf2f(u16 u) {
    return __builtin_bit_cast(float, (u32)u << 16);
}
__device__ __forceinline__ u32 pack2bf(float a, float b) {
    return (u32)f2bf(a) | ((u32)f2bf(b) << 16);
}

// ======================================================================
// fp32 -> bf16 cast, 8 elems/thread
// ======================================================================
__global__ __launch_bounds__(256)
void cast_k(const float* __restrict__ src, u16* __restrict__ dst, int n8) {
    int t = blockIdx.x * 256 + threadIdx.x;
    if (t >= n8) return;
    const float* s = src + (size_t)t * 8;
    float4 a = *(const float4*)(s);
    float4 b = *(const float4*)(s + 4);
    s16x8 o;
    o[0] = (short)f2bf(a.x); o[1] = (short)f2bf(a.y);
    o[2] = (short)f2bf(a.z); o[3] = (short)f2bf(a.w);
    o[4] = (short)f2bf(b.x); o[5] = (short)f2bf(b.y);
    o[6] = (short)f2bf(b.z); o[7] = (short)f2bf(b.w);
    *(s16x8*)(dst + (size_t)t * 8) = o;
}

// in_w cast with wq rows (row%1536 < 512) pre-scaled by QSC_
__global__ __launch_bounds__(256)
void castq_k(const float* __restrict__ src, u16* __restrict__ dst, int n8) {
    int t = blockIdx.x * 256 + threadIdx.x;
    if (t >= n8) return;
    int row = t >> 6;                  // 512 cols / 8 per chunk
    float sc = (row % 1536) < 512 ? QSC_ : 1.0f;
    const float* s = src + (size_t)t * 8;
    float4 a = *(const float4*)(s);
    float4 b = *(const float4*)(s + 4);
    s16x8 o;
    o[0] = (short)f2bf(a.x * sc); o[1] = (short)f2bf(a.y * sc);
    o[2] = (short)f2bf(a.z * sc); o[3] = (short)f2bf(a.w * sc);
    o[4] = (short)f2bf(b.x * sc); o[5] = (short)f2bf(b.y * sc);
    o[6] = (short)f2bf(b.z * sc); o[7] = (short)f2bf(b.w * sc);
    *(s16x8*)(dst + (size_t)t * 8) = o;
}

// scaled q/k bias: qbs[i][j] = in_b[i*1536+j] * (j<512?QSC:1)
__global__ __launch_bounds__(256)
void qbias_k(const float* __restrict__ ib, float* __restrict__ qbs) {
    int t = blockIdx.x * 256 + threadIdx.x;
    if (t >= NL_ * 1024) return;
    int i = t >> 10, j = t & 1023;
    float sc = j < 512 ? QSC_ : 1.0f;
    qbs[t] = ib[i * 1536 + j] * sc;
}

// h1_w left half [128, 0:512] (row stride 1024) -> packed bf16 [128,512]
__global__ __launch_bounds__(256)
void h1cast_k(const float* __restrict__ src, u16* __restrict__ dst) {
    int t = blockIdx.x * 256 + threadIdx.x;
    if (t >= 128 * 512 / 8) return;
    int row = t >> 6, c8 = (t & 63) << 3;
    const float* s = src + (size_t)row * 1024 + c8;
    float4 a = *(const float4*)(s);
    float4 b = *(const float4*)(s + 4);
    s16x8 o;
    o[0] = (short)f2bf(a.x); o[1] = (short)f2bf(a.y);
    o[2] = (short)f2bf(a.z); o[3] = (short)f2bf(a.w);
    o[4] = (short)f2bf(b.x); o[5] = (short)f2bf(b.y);
    o[6] = (short)f2bf(b.z); o[7] = (short)f2bf(b.w);
    *(s16x8*)(dst + (size_t)row * 512 + c8) = o;
}

// ======================================================================
// RoPE cos/sin tables
// ======================================================================
__global__ void tables_k(float* __restrict__ ct, float* __restrict__ st) {
    int idx = blockIdx.x * blockDim.x + threadIdx.x;
    if (idx >= L_ * DH_) return;
    int l = idx / DH_;
    int d = idx % DH_;
    int j = d & 31;
    float invf = powf(10000.0f, -(float)(2 * j) / (float)DH_);
    float ang = (float)l * invf;
    ct[idx] = cosf(ang);
    st[idx] = sinf(ang);
}

// ======================================================================
// bf16 MFMA GEMM (reg-staged): C = act(A @ W^T + bias)(+resid bf16)
// 128x128 tile, BK=64, 512 threads / 8 waves (2x4), wave tile 64x32
// (4x2 16x16 frags). Doubled waves/SIMD vs 4-wave config for latency
// hiding on short-N GEMMs (grid-limited to 2 blocks/CU at N=512).
// ======================================================================
template<bool RELU, bool RESID, bool OUTBF, bool ROWBIAS>
__global__ __launch_bounds__(512)
void mgemm_k(const u16* __restrict__ A, const u16* __restrict__ W,
             const float* __restrict__ bias, const u16* __restrict__ resid,
             void* __restrict__ Cout, int M, int N, int K)
{
    constexpr int LDT = 72;               // padded LDS row stride (bf16)
    __shared__ u16 As[128 * LDT];
    __shared__ u16 Ws[128 * LDT];
    const int nt = N >> 7;
    const int bx = blockIdx.x % nt;
    const int by = blockIdx.x / nt;
    const int m0 = by << 7, n0 = bx << 7;
    const int tid = threadIdx.x;
    const int lane = tid & 63, wid = tid >> 6;
    const int wr = wid >> 2, wc = wid & 3;     // 2x4 wave grid
    const int lr = lane & 15, lk = lane >> 4;

    f32x4 acc[4][2];
#pragma unroll
    for (int m = 0; m < 4; m++)
#pragma unroll
        for (int n = 0; n < 2; n++) acc[m][n] = (f32x4)0.0f;

    for (int k0 = 0; k0 < K; k0 += 64) {
        s16x8 va[2], vw[2];
#pragma unroll
        for (int u = 0; u < 2; u++) {
            int ch = tid + (u << 9);          // 16B chunk id, 0..1023
            int r = ch >> 3, c8 = (ch & 7) << 3;
            int ar = m0 + r; if (ar >= M) ar = M - 1;
            va[u] = *(const s16x8*)(A + (size_t)ar * K + k0 + c8);
            vw[u] = *(const s16x8*)(W + (size_t)(n0 + r) * K + k0 + c8);
        }
        __syncthreads();   // previous iteration's LDS reads complete
#pragma unroll
        for (int u = 0; u < 2; u++) {
            int ch = tid + (u << 9);
            int r = ch >> 3, c8 = (ch & 7) << 3;
            *(s16x8*)&As[r * LDT + c8] = va[u];
            *(s16x8*)&Ws[r * LDT + c8] = vw[u];
        }
        __syncthreads();   // tiles staged
#pragma unroll
        for (int kk = 0; kk < 2; kk++) {
            s16x8 af[4], bf[2];
#pragma unroll
            for (int m = 0; m < 4; m++)
                af[m] = *(const s16x8*)&As[(wr * 64 + m * 16 + lr) * LDT + kk * 32 + lk * 8];
#pragma unroll
            for (int n = 0; n < 2; n++)
                bf[n] = *(const s16x8*)&Ws[(wc * 32 + n * 16 + lr) * LDT + kk * 32 + lk * 8];
#pragma unroll
            for (int m = 0; m < 4; m++)
#pragma unroll
                for (int n = 0; n < 2; n++)
                    acc[m][n] = __builtin_amdgcn_mfma_f32_16x16x32_bf16(
                        af[m], bf[n], acc[m][n], 0, 0, 0);
        }
    }

    float bv[2];
    if constexpr (!ROWBIAS) {
#pragma unroll
        for (int n = 0; n < 2; n++) bv[n] = bias[n0 + wc * 32 + n * 16 + lr];
    }
#pragma unroll
    for (int m = 0; m < 4; m++) {
#pragma unroll
        for (int j = 0; j < 4; j++) {
            int row = m0 + wr * 64 + m * 16 + lk * 4 + j;
            if (row >= M) continue;
            const float* rb = nullptr;
            if constexpr (ROWBIAS) rb = bias + (size_t)(row / L_) * N;
#pragma unroll
            for (int n = 0; n < 2; n++) {
                int col = n0 + wc * 32 + n * 16 + lr;
                float c = acc[m][n][j];
                if constexpr (ROWBIAS) c += rb[col];
                else                   c += bv[n];
                if constexpr (RELU) c = fmaxf(c, 0.0f);
                if constexpr (RESID) c += bf2f(resid[(size_t)row * N + col]);
                if constexpr (OUTBF) ((u16*)Cout)[(size_t)row * N + col] = f2bf(c);
                else                 ((float*)Cout)[(size_t)row * N + col] = c;
            }
        }
    }
}

// ======================================================================
// LayerNorm: one wave per row; RELU / bf16-out / bf16-in / fused-RoPE.
// ROPE: additionally writes rope(ln_out) to rout (partner via shfl_xor 4:
// d±32 within the 64-dim head = ±4 lanes; head = 8-lane group, xor stays
// inside it).
// ======================================================================
template<int DD, bool RELU, bool OUTBF, bool INBF, bool ROPE>
__global__ __launch_bounds__(256)
void ln_k(const void* __restrict__ xin, const float* __restrict__ s,
          const float* __restrict__ bb, void* __restrict__ out, int M,
          const float* __restrict__ ct = nullptr,
          const float* __restrict__ st = nullptr,
          u16* __restrict__ rout = nullptr)
{
    const int lane = threadIdx.x & 63;
    const int row = (blockIdx.x << 2) + (threadIdx.x >> 6);
    if (row >= M) return;
    constexpr int NV = DD / 64;
    float v[NV];
    if constexpr (INBF) {
        const u16* xr = (const u16*)xin + (size_t)row * DD;
        if constexpr (NV == 8) {
            s16x8 t = *(const s16x8*)(xr + lane * 8);
#pragma unroll
            for (int e = 0; e < 8; e++) v[e] = bf2f((u16)t[e]);
        } else {
            v[0] = bf2f(xr[lane * 2]); v[1] = bf2f(xr[lane * 2 + 1]);
        }
    } else {
        const float* xr = (const float*)xin + (size_t)row * DD;
        if constexpr (NV == 8) {
            *(float4*)(v)     = *(const float4*)(xr + lane * 8);
            *(float4*)(v + 4) = *(const float4*)(xr + lane * 8 + 4);
        } else {
            float2 t = *(const float2*)(xr + lane * 2);
            v[0] = t.x; v[1] = t.y;
        }
    }
    float sum = 0.f, sq = 0.f;
#pragma unroll
    for (int e = 0; e < NV; e++) { sum += v[e]; sq += v[e] * v[e]; }
#pragma unroll
    for (int msk = 1; msk < 64; msk <<= 1) {
        sum += __shfl_xor(sum, msk);
        sq  += __shfl_xor(sq, msk);
    }
    const float mean = sum * (1.0f / DD);
    const float var  = sq * (1.0f / DD) - mean * mean;
    const float rstd = rsqrtf(var + EPS_);
#pragma unroll
    for (int e = 0; e < NV; e++) {
        int d = lane * NV + e;
        float r = (v[e] - mean) * rstd * s[d] + bb[d];
        if constexpr (RELU) r = fmaxf(r, 0.0f);
        v[e] = r;
    }
    if constexpr (OUTBF) {
        u16* orow = (u16*)out + (size_t)row * DD;
        if constexpr (NV == 8) {
            s16x8 o;
#pragma unroll
            for (int e = 0; e < 8; e++) o[e] = (short)f2bf(v[e]);
            *(s16x8*)(orow + lane * 8) = o;
        } else {
            orow[lane * 2] = f2bf(v[0]); orow[lane * 2 + 1] = f2bf(v[1]);
        }
    } else {
        float* orow = (float*)out + (size_t)row * DD;
        if constexpr (NV == 8) {
            *(float4*)(orow + lane * 8)     = *(float4*)(v);
            *(float4*)(orow + lane * 8 + 4) = *(float4*)(v + 4);
        } else {
            float2 t; t.x = v[0]; t.y = v[1];
            *(float2*)(orow + lane * 2) = t;
        }
    }
    if constexpr (ROPE) {
        // partner values (d +/- 32) live 4 lanes away
        float pv[8];
#pragma unroll
        for (int e = 0; e < 8; e++) pv[e] = __shfl_xor(v[e], 4);
        const int l = row % L_;
        const int dd0 = (lane & 7) * 8;       // dd base within head
        const float sgn = (lane & 4) ? 1.0f : -1.0f;
        float4 c0 = *(const float4*)(ct + l * DH_ + dd0);
        float4 c1 = *(const float4*)(ct + l * DH_ + dd0 + 4);
        float4 s0 = *(const float4*)(st + l * DH_ + dd0);
        float4 s1 = *(const float4*)(st + l * DH_ + dd0 + 4);
        float cc[8] = {c0.x,c0.y,c0.z,c0.w,c1.x,c1.y,c1.z,c1.w};
        float ss[8] = {s0.x,s0.y,s0.z,s0.w,s1.x,s1.y,s1.z,s1.w};
        s16x8 ro;
#pragma unroll
        for (int e = 0; e < 8; e++)
            ro[e] = (short)f2bf(v[e] * cc[e] + sgn * pv[e] * ss[e]);
        *(s16x8*)(rout + (size_t)row * DD + lane * 8) = ro;
    }
}

// ======================================================================
// MFMA flash attention, swapped-operand (S^T = K Q^T), in-register
// softmax in exp2 domain (Q pre-scaled). r8/r11-proven structure.
// ======================================================================
__global__ __launch_bounds__(256)
void attn_k(const u16* __restrict__ qk, const u16* __restrict__ v,
            const float* __restrict__ mask, u16* __restrict__ o)
{
    constexpr int LDA = 68;
    __shared__ u16 Kt[64 * LDA];
    __shared__ u16 Vt[64 * LDA];
    const int bh = blockIdx.x >> 4, qt = blockIdx.x & 15;
    const int b = bh >> 3, h = bh & 7;
    const int tid = threadIdx.x;
    const int lane = tid & 63, w = tid >> 6;
    const int lr = lane & 15, lg = lane >> 4;
    const size_t basebl = (size_t)b * L_;

    const int qrow = qt * 64 + w * 16 + lr;
    const int qc = qrow < L_ ? qrow : L_ - 1;
    s16x8 bq[2];
#pragma unroll
    for (int kk = 0; kk < 2; kk++)
        bq[kk] = *(const s16x8*)(qk + (basebl + qc) * 1024 + h * DH_ + kk * 32 + lg * 8);

    f32x4 oacc[4];            // O^T: col q=lr, rows d = 16*n2 + 4*lg + j
#pragma unroll
    for (int n = 0; n < 4; n++) oacc[n] = (f32x4)0.0f;
    float m_run = -1e30f, l_run = 0.f;

    const int st_key = tid >> 3;          // 0..31 (+32 for u=1)
    const int st_d8 = (tid & 7) << 3;
    const int src0 = lr + ((lane & 16) << 1);   // lr + 32*(lg&1)
    const int src1 = src0 + 16;
    const bool ahi = (lg >> 1) != 0;

    for (int kt = 0; kt < 16; kt++) {
        __syncthreads();          // all waves done reading prev Kt/Vt
#pragma unroll
        for (int u = 0; u < 2; u++) {
            int key = st_key + u * 32;
            int gk = kt * 64 + key; if (gk >= L_) gk = L_ - 1;
            s16x8 kv = *(const s16x8*)(qk + (basebl + gk) * 1024 + 512 + h * DH_ + st_d8);
            s16x8 vv = *(const s16x8*)(v  + (basebl + gk) * D_ + h * DH_ + st_d8);
            *(s16x8*)&Kt[key * LDA + st_d8] = kv;
#pragma unroll
            for (int e = 0; e < 8; e++) Vt[(st_d8 + e) * LDA + key] = (u16)vv[e];
        }
        __syncthreads();

        int gkey = kt * 64 + lane;
        bool vb = (gkey < L_) && (mask[basebl + gkey] > 0.0f);
        u64 vm = __ballot(vb);

        f32x4 sacc[4];
#pragma unroll
        for (int n = 0; n < 4; n++) {
            sacc[n] = (f32x4)0.0f;
#pragma unroll
            for (int kk = 0; kk < 2; kk++) {
                s16x8 ak = *(const s16x8*)&Kt[(n * 16 + lr) * LDA + kk * 32 + lg * 8];
                sacc[n] = __builtin_amdgcn_mfma_f32_16x16x32_bf16(ak, bq[kk], sacc[n], 0, 0, 0);
            }
        }

        float p[4][4];
        float tm = -1e30f;
#pragma unroll
        for (int n = 0; n < 4; n++)
#pragma unroll
            for (int j = 0; j < 4; j++) {
                int kl = 16 * n + 4 * lg + j;
                float s = ((vm >> kl) & 1ull) ? sacc[n][j] : -1e30f;
                p[n][j] = s;
                tm = fmaxf(tm, s);
            }
        tm = fmaxf(tm, __shfl_xor(tm, 16));
        tm = fmaxf(tm, __shfl_xor(tm, 32));
        float nm = fmaxf(m_run, tm);
        float corr = exp2f(m_run - nm);
        m_run = nm;
        float ts = 0.f;
#pragma unroll
        for (int n = 0; n < 4; n++)
#pragma unroll
            for (int j = 0; j < 4; j++) {
                p[n][j] = exp2f(p[n][j] - nm);
                ts += p[n][j];
            }
        ts += __shfl_xor(ts, 16);
        ts += __shfl_xor(ts, 32);
        l_run = l_run * corr + ts;
#pragma unroll
        for (int n = 0; n < 4; n++) oacc[n] *= corr;

        u32 pk[4][2];
#pragma unroll
        for (int n = 0; n < 4; n++) {
            pk[n][0] = pack2bf(p[n][0], p[n][1]);
            pk[n][1] = pack2bf(p[n][2], p[n][3]);
        }
        u32 r0[4][2], r1[4][2];
#pragma unroll
        for (int n = 0; n < 4; n++)
#pragma unroll
            for (int i = 0; i < 2; i++) {
                r0[n][i] = (u32)__shfl((int)pk[n][i], src0);
                r1[n][i] = (u32)__shfl((int)pk[n][i], src1);
            }
#pragma unroll
        for (int kk = 0; kk < 2; kk++) {
            u32x4 bw;
            bw[0] = ahi ? r0[2 * kk + 1][0] : r0[2 * kk][0];
            bw[1] = ahi ? r0[2 * kk + 1][1] : r0[2 * kk][1];
            bw[2] = ahi ? r1[2 * kk + 1][0] : r1[2 * kk][0];
            bw[3] = ahi ? r1[2 * kk + 1][1] : r1[2 * kk][1];
            s16x8 bp = __builtin_bit_cast(s16x8, bw);
#pragma unroll
            for (int n2 = 0; n2 < 4; n2++) {
                s16x8 av = *(const s16x8*)&Vt[(n2 * 16 + lr) * LDA + kk * 32 + lg * 8];
                oacc[n2] = __builtin_amdgcn_mfma_f32_16x16x32_bf16(av, bp, oacc[n2], 0, 0, 0);
            }
        }
    }

    __syncthreads();   // all waves done with Kt/Vt MFMA reads
    u16* Ol = &Kt[w * 16 * LDA];
    float inv = 1.0f / l_run;
#pragma unroll
    for (int n = 0; n < 4; n++)
#pragma unroll
        for (int j = 0; j < 4; j++)
            Ol[lr * LDA + 16 * n + 4 * lg + j] = f2bf(oacc[n][j] * inv);
    int orow = lane >> 2, oc = (lane & 3) * 16;
    int qg = qt * 64 + w * 16 + orow;
    if (qg < L_) {
        s16x8 o0 = *(const s16x8*)&Ol[orow * LDA + oc];
        s16x8 o1 = *(const s16x8*)&Ol[orow * LDA + oc + 8];
        *(s16x8*)(o + (basebl + qg) * D_ + h * DH_ + oc) = o0;
        *(s16x8*)(o + (basebl + qg) * D_ + h * DH_ + oc + 8) = o1;
    }
}

// ======================================================================
// masked mean pool, two-stage (X bf16).
// ======================================================================
__global__ __launch_bounds__(512)
void pool1_k(const u16* __restrict__ x, const float* __restrict__ mask,
             float* __restrict__ pp, float* __restrict__ mp)
{
    const int b = blockIdx.x, sp = blockIdx.y;
    const int d = threadIdx.x;
    const int l0 = sp * 64;
    float acc = 0.f;
    for (int l = l0; l < l0 + 64 && l < L_; l++)
        acc += bf2f(x[((size_t)b * L_ + l) * D_ + d]) * mask[b * L_ + l];
    pp[((size_t)b * 16 + sp) * D_ + d] = acc;
    if (d == 0) {
        float ms = 0.f;
        for (int l = l0; l < l0 + 64 && l < L_; l++) ms += mask[b * L_ + l];
        mp[b * 16 + sp] = ms;
    }
}

__global__ __launch_bounds__(512)
void pool2_k(const float* __restrict__ pp, const float* __restrict__ mp,
             float* __restrict__ g)
{
    const int b = blockIdx.x;
    const int d = threadIdx.x;
    float acc = 0.f, ms = 0.f;
#pragma unroll
    for (int sp = 0; sp < 16; sp++) {
        acc += pp[((size_t)b * 16 + sp) * D_ + d];
        ms += mp[b * 16 + sp];
    }
    g[b * D_ + d] = acc / ms;
}

// ======================================================================
// gpart[b][j] = h1_b[j] + dot(gctx[b], h1_w[j, 512:1024])  (fp32)
// ======================================================================
__global__ __launch_bounds__(256)
void gpart_k(const float* __restrict__ g, const float* __restrict__ h1w,
             const float* __restrict__ h1b, float* __restrict__ gp)
{
    const int lane = threadIdx.x & 63;
    const int gid = (blockIdx.x << 2) + (threadIdx.x >> 6);
    const int b = gid >> 7, j = gid & 127;
    const float* wr = h1w + (size_t)j * (2 * D_) + D_;
    const float* gr = g + b * D_;
    float4 a0 = *(const float4*)(gr + lane * 8);
    float4 a1 = *(const float4*)(gr + lane * 8 + 4);
    float4 w0 = *(const float4*)(wr + lane * 8);
    float4 w1v = *(const float4*)(wr + lane * 8 + 4);
    float acc = a0.x * w0.x + a0.y * w0.y + a0.z * w0.z + a0.w * w0.w
              + a1.x * w1v.x + a1.y * w1v.y + a1.z * w1v.z + a1.w * w1v.w;
#pragma unroll
    for (int msk = 1; msk < 64; msk <<= 1) acc += __shfl_xor(acc, msk);
    if (lane == 0) gp[b * 128 + j] = acc + h1b[j];
}

// ======================================================================
// logits[m] = h2_b + dot(h[m,0:128], h2_w)
// ======================================================================
__global__ __launch_bounds__(256)
void logits_k(const float* __restrict__ h, const float* __restrict__ w,
              const float* __restrict__ bsc, float* __restrict__ out, int M)
{
    const int lane = threadIdx.x & 63;
    const int row = (blockIdx.x << 2) + (threadIdx.x >> 6);
    if (row >= M) return;
    float2 hv = *(const float2*)(h + (size_t)row * 128 + lane * 2);
    float2 wv = *(const float2*)(w + lane * 2);
    float acc = hv.x * wv.x + hv.y * wv.y;
#pragma unroll
    for (int msk = 1; msk < 64; msk <<= 1) acc += __shfl_xor(acc, msk);
    if (lane == 0) out[row] = acc + bsc[0];
}

// ======================================================================
// host orchestration
// ======================================================================
extern "C" void kernel_launch(void* const* d_in, const int* in_sizes, int n_in,
                              void* d_out, int out_size, void* d_ws, size_t ws_size,
                              hipStream_t stream)
{
    const float* emb       = (const float*)d_in[0];
    const float* mask      = (const float*)d_in[1];
    const float* proj_w    = (const float*)d_in[3];
    const float* proj_b    = (const float*)d_in[4];
    const float* proj_ln_s = (const float*)d_in[5];
    const float* proj_ln_b = (const float*)d_in[6];
    const float* ln1_s     = (const float*)d_in[7];
    const float* ln1_b     = (const float*)d_in[8];
    const float* in_w      = (const float*)d_in[9];
    const float* in_b      = (const float*)d_in[10];
    const float* out_w     = (const float*)d_in[11];
    const float* out_b     = (const float*)d_in[12];
    const float* ln2_s     = (const float*)d_in[13];
    const float* ln2_b     = (const float*)d_in[14];
    const float* w1        = (const float*)d_in[15];
    const float* b1        = (const float*)d_in[16];
    const float* w2        = (const float*)d_in[17];
    const float* b2        = (const float*)d_in[18];
    const float* h1_w      = (const float*)d_in[19];
    const float* h1_b      = (const float*)d_in[20];
    const float* hln_s     = (const float*)d_in[21];
    const float* hln_b     = (const float*)d_in[22];
    const float* h2_w      = (const float*)d_in[23];
    const float* h2_b      = (const float*)d_in[24];
    float* out = (float*)d_out;

    // Workspace map (S = BL*D floats):
    //   [0,0.5S)   X bf16 residual stream [BL,512]
    //   [S,2S)     Rf fp32 (proj-out, head Hb) / QKB bf16 [BL,1024] (disjoint)
    //   [2S,2.5S)  VB bf16
    //   [2.5S,3S)  NbB bf16
    //   [3S,5S)    FFb16 bf16 [BL,2048]; aliases embB, RopeB, RB (disjoint)
    //   [5S,...)   bf16 weights, CT/ST/GC/GP/Pp/Mp/QBS
    float* ws = (float*)d_ws;
    const size_t S = (size_t)BL_ * D_;
    u16* X = (u16*)ws;                    // bf16 residual
    float* Rf = ws + S;
    u16* QKB   = (u16*)(ws + S);
    u16* VB    = (u16*)(ws + 2 * S);
    u16* NbB   = (u16*)(ws + 2 * S) + S;
    u16* FFb16 = (u16*)(ws + 3 * S);
    u16* RopeB = FFb16;
    u16* embB  = FFb16;
    u16* RB    = (u16*)(ws + 4 * S);
    u16* projwB = (u16*)(ws + 5 * S);
    u16* iwB  = projwB + 512 * 1280;
    u16* owB  = iwB + (size_t)NL_ * 3 * D_ * D_;
    u16* w1B  = owB + (size_t)NL_ * D_ * D_;
    u16* w2B  = w1B + (size_t)NL_ * FF_ * D_;
    u16* h1wB = w2B + (size_t)NL_ * D_ * FF_;
    float* CT = ws + 5 * S + 6651904;
    float* ST = CT + L_ * DH_;
    float* GC = ST + L_ * DH_;
    float* GP = GC + B_ * D_;
    float* Pp = GP + B_ * 128;            // [B*16, 512] partials
    float* Mp = Pp + (size_t)B_ * 16 * D_;
    float* QBS = Mp + B_ * 16;            // [NL,1024] scaled q/k bias
    float* Hb = Rf;

    const int MT = 128;
    const dim3 blk(256);
    const dim3 gblk(512);
    const int lnGrid = (BL_ + 3) / 4;

    cast_k<<<(BL_ * E_ / 8 + 255) / 256, blk, 0, stream>>>(emb, embB, BL_ * E_ / 8);
    cast_k<<<(512 * 1280 / 8 + 255) / 256, blk, 0, stream>>>(proj_w, projwB, 512 * 1280 / 8);
    castq_k<<<(NL_ * 3 * D_ * D_ / 8 + 255) / 256, blk, 0, stream>>>(in_w, iwB, NL_ * 3 * D_ * D_ / 8);
    qbias_k<<<(NL_ * 1024 + 255) / 256, blk, 0, stream>>>(in_b, QBS);
    cast_k<<<(NL_ * D_ * D_ / 8 + 255) / 256, blk, 0, stream>>>(out_w, owB, NL_ * D_ * D_ / 8);
    cast_k<<<(NL_ * FF_ * D_ / 8 + 255) / 256, blk, 0, stream>>>(w1, w1B, NL_ * FF_ * D_ / 8);
    cast_k<<<(NL_ * D_ * FF_ / 8 + 255) / 256, blk, 0, stream>>>(w2, w2B, NL_ * D_ * FF_ / 8);
    h1cast_k<<<(128 * 512 / 8 + 255) / 256, blk, 0, stream>>>(h1_w, h1wB);
    tables_k<<<(L_ * DH_ + 255) / 256, blk, 0, stream>>>(CT, ST);

    mgemm_k<false,false,false,false><<<MT * (D_ / 128), gblk, 0, stream>>>(
        embB, projwB, proj_b, nullptr, Rf, BL_, D_, E_);
    ln_k<D_,false,true,false,false><<<lnGrid, blk, 0, stream>>>(Rf, proj_ln_s, proj_ln_b, X, BL_);

    for (int i = 0; i < NL_; i++) {
        const u16* iw = iwB + (size_t)i * 3 * D_ * D_;
        const float* ib = in_b + (size_t)i * 3 * D_;
        // fused ln1 + rope: writes NbB (LN out) and RopeB (roped LN out)
        ln_k<D_,false,true,true,true><<<lnGrid, blk, 0, stream>>>(
            X, ln1_s + i * D_, ln1_b + i * D_, NbB, BL_, CT, ST, RopeB);
        mgemm_k<false,false,true,false><<<MT * 4, gblk, 0, stream>>>(
            NbB, iw + 2 * D_ * D_, ib + 2 * D_, nullptr, VB, BL_, D_, D_);
        // fused q+k projection (wq pre-scaled by QSC_, bias = QBS[i])
        mgemm_k<false,false,true,false><<<MT * 8, gblk, 0, stream>>>(
            RopeB, iw, QBS + (size_t)i * 1024, nullptr, QKB, BL_, 1024, D_);
        attn_k<<<B_ * H_ * 16, blk, 0, stream>>>(QKB, VB, mask, RB);
        mgemm_k<false,true,true,false><<<MT * 4, gblk, 0, stream>>>(
            RB, owB + (size_t)i * D_ * D_, out_b + i * D_, X, X, BL_, D_, D_);
        ln_k<D_,false,true,true,false><<<lnGrid, blk, 0, stream>>>(
            X, ln2_s + i * D_, ln2_b + i * D_, NbB, BL_);
        mgemm_k<true,false,true,false><<<MT * 16, gblk, 0, stream>>>(
            NbB, w1B + (size_t)i * FF_ * D_, b1 + i * FF_, nullptr, FFb16, BL_, FF_, D_);
        mgemm_k<false,true,true,false><<<MT * 4, gblk, 0, stream>>>(
            FFb16, w2B + (size_t)i * D_ * FF_, b2 + i * D_, X, X, BL_, D_, FF_);
    }

    pool1_k<<<dim3(B_, 16), dim3(512), 0, stream>>>(X, mask, Pp, Mp);
    pool2_k<<<B_, dim3(512), 0, stream>>>(Pp, Mp, GC);
    gpart_k<<<(B_ * 128) / 4, blk, 0, stream>>>(GC, h1_w, h1_b, GP);
    mgemm_k<false,false,false,true><<<MT * 1, gblk, 0, stream>>>(
        X, h1wB, GP, nullptr, Hb, BL_, 128, D_);
    ln_k<128,true,false,false,false><<<lnGrid, blk, 0, stream>>>(Hb, hln_s, hln_b, Hb, BL_);
    logits_k<<<lnGrid, blk, 0, stream>>>(Hb, h2_w, h2_b, out, BL_);
}

// Round 13
// 1387.111 us; speedup vs baseline: 1.0819x; 1.0185x over previous
//
#include <hip/hip_runtime.h>
#include <cstdint>
#include <cstddef>

// ---------------- problem constants ----------------
#define B_   16
#define L_   1022
#define E_   1280
#define D_   512
#define H_   8
#define FF_  2048
#define NL_  4
#define DH_  64
#define BL_  (B_*L_)      // 16352
#define EPS_ 1e-5f
#define QSC_ 0.18033688011112042f   // 0.125 * log2(e)

typedef unsigned short u16;
typedef unsigned int   u32;
typedef unsigned long long u64;
typedef float f32x4 __attribute__((ext_vector_type(4)));
typedef short s16x8 __attribute__((ext_vector_type(8)));
typedef u32 u32x4 __attribute__((ext_vector_type(4)));

__device__ __forceinline__ u16 f2bf(float f) {
    u32 u = __builtin_bit_cast(u32, f);
    u += 0x7fffu + ((u >> 16) & 1u);
    return (u16)(u >> 16);
}
__device__ __forceinline__ float bf2f(u16 u) {
    return __builtin_bit_cast(float, (u32)u << 16);
}
__device__ __forceinline__ u32 pack2bf(float a, float b) {
    return (u32)f2bf(a) | ((u32)f2bf(b) << 16);
}

// ======================================================================
// fp32 -> bf16 cast, 8 elems/thread
// ======================================================================
__global__ __launch_bounds__(256)
void cast_k(const float* __restrict__ src, u16* __restrict__ dst, int n8) {
    int t = blockIdx.x * 256 + threadIdx.x;
    if (t >= n8) return;
    const float* s = src + (size_t)t * 8;
    float4 a = *(const float4*)(s);
    float4 b = *(const float4*)(s + 4);
    s16x8 o;
    o[0] = (short)f2bf(a.x); o[1] = (short)f2bf(a.y);
    o[2] = (short)f2bf(a.z); o[3] = (short)f2bf(a.w);
    o[4] = (short)f2bf(b.x); o[5] = (short)f2bf(b.y);
    o[6] = (short)f2bf(b.z); o[7] = (short)f2bf(b.w);
    *(s16x8*)(dst + (size_t)t * 8) = o;
}

// in_w cast with wq rows (row%1536 < 512) pre-scaled by QSC_
__global__ __launch_bounds__(256)
void castq_k(const float* __restrict__ src, u16* __restrict__ dst, int n8) {
    int t = blockIdx.x * 256 + threadIdx.x;
    if (t >= n8) return;
    int row = t >> 6;                  // 512 cols / 8 per chunk
    float sc = (row % 1536) < 512 ? QSC_ : 1.0f;
    const float* s = src + (size_t)t * 8;
    float4 a = *(const float4*)(s);
    float4 b = *(const float4*)(s + 4);
    s16x8 o;
    o[0] = (short)f2bf(a.x * sc); o[1] = (short)f2bf(a.y * sc);
    o[2] = (short)f2bf(a.z * sc); o[3] = (short)f2bf(a.w * sc);
    o[4] = (short)f2bf(b.x * sc); o[5] = (short)f2bf(b.y * sc);
    o[6] = (short)f2bf(b.z * sc); o[7] = (short)f2bf(b.w * sc);
    *(s16x8*)(dst + (size_t)t * 8) = o;
}

// scaled q/k bias: qbs[i][j] = in_b[i*1536+j] * (j<512?QSC:1)
__global__ __launch_bounds__(256)
void qbias_k(const float* __restrict__ ib, float* __restrict__ qbs) {
    int t = blockIdx.x * 256 + threadIdx.x;
    if (t >= NL_ * 1024) return;
    int i = t >> 10, j = t & 1023;
    float sc = j < 512 ? QSC_ : 1.0f;
    qbs[t] = ib[i * 1536 + j] * sc;
}

// h1_w left half [128, 0:512] (row stride 1024) -> packed bf16 [128,512]
__global__ __launch_bounds__(256)
void h1cast_k(const float* __restrict__ src, u16* __restrict__ dst) {
    int t = blockIdx.x * 256 + threadIdx.x;
    if (t >= 128 * 512 / 8) return;
    int row = t >> 6, c8 = (t & 63) << 3;
    const float* s = src + (size_t)row * 1024 + c8;
    float4 a = *(const float4*)(s);
    float4 b = *(const float4*)(s + 4);
    s16x8 o;
    o[0] = (short)f2bf(a.x); o[1] = (short)f2bf(a.y);
    o[2] = (short)f2bf(a.z); o[3] = (short)f2bf(a.w);
    o[4] = (short)f2bf(b.x); o[5] = (short)f2bf(b.y);
    o[6] = (short)f2bf(b.z); o[7] = (short)f2bf(b.w);
    *(s16x8*)(dst + (size_t)row * 512 + c8) = o;
}

// ======================================================================
// RoPE cos/sin tables
// ======================================================================
__global__ void tables_k(float* __restrict__ ct, float* __restrict__ st) {
    int idx = blockIdx.x * blockDim.x + threadIdx.x;
    if (idx >= L_ * DH_) return;
    int l = idx / DH_;
    int d = idx % DH_;
    int j = d & 31;
    float invf = powf(10000.0f, -(float)(2 * j) / (float)DH_);
    float ang = (float)l * invf;
    ct[idx] = cosf(ang);
    st[idx] = sinf(ang);
}

// ======================================================================
// bf16 MFMA GEMM (reg-staged, software-pipelined): C = act(A@W^T+b)(+res)
// 128x128 tile, BK=64, 512 threads / 8 waves (2x4), wave tile 64x32.
// Loads for step k+1 issued right after staging barrier -> in flight
// under the MFMA phase (hides ~300-900cy global latency).
// ======================================================================
template<bool RELU, bool RESID, bool OUTBF, bool ROWBIAS>
__global__ __launch_bounds__(512)
void mgemm_k(const u16* __restrict__ A, const u16* __restrict__ W,
             const float* __restrict__ bias, const u16* __restrict__ resid,
             void* __restrict__ Cout, int M, int N, int K)
{
    constexpr int LDT = 72;               // padded LDS row stride (bf16)
    __shared__ u16 As[128 * LDT];
    __shared__ u16 Ws[128 * LDT];
    const int nt = N >> 7;
    const int bx = blockIdx.x % nt;
    const int by = blockIdx.x / nt;
    const int m0 = by << 7, n0 = bx << 7;
    const int tid = threadIdx.x;
    const int lane = tid & 63, wid = tid >> 6;
    const int wr = wid >> 2, wc = wid & 3;     // 2x4 wave grid
    const int lr = lane & 15, lk = lane >> 4;

    f32x4 acc[4][2];
#pragma unroll
    for (int m = 0; m < 4; m++)
#pragma unroll
        for (int n = 0; n < 2; n++) acc[m][n] = (f32x4)0.0f;

    s16x8 va[2], vw[2];
    auto load_tiles = [&](int k0) {
#pragma unroll
        for (int u = 0; u < 2; u++) {
            int ch = tid + (u << 9);          // 16B chunk id, 0..1023
            int r = ch >> 3, c8 = (ch & 7) << 3;
            int ar = m0 + r; if (ar >= M) ar = M - 1;
            va[u] = *(const s16x8*)(A + (size_t)ar * K + k0 + c8);
            vw[u] = *(const s16x8*)(W + (size_t)(n0 + r) * K + k0 + c8);
        }
    };

    load_tiles(0);
    for (int k0 = 0; k0 < K; k0 += 64) {
        __syncthreads();   // previous iteration's LDS reads complete
#pragma unroll
        for (int u = 0; u < 2; u++) {
            int ch = tid + (u << 9);
            int r = ch >> 3, c8 = (ch & 7) << 3;
            *(s16x8*)&As[r * LDT + c8] = va[u];
            *(s16x8*)&Ws[r * LDT + c8] = vw[u];
        }
        __syncthreads();   // tiles staged
        if (k0 + 64 < K) load_tiles(k0 + 64);   // prefetch under MFMA
#pragma unroll
        for (int kk = 0; kk < 2; kk++) {
            s16x8 af[4], bf[2];
#pragma unroll
            for (int m = 0; m < 4; m++)
                af[m] = *(const s16x8*)&As[(wr * 64 + m * 16 + lr) * LDT + kk * 32 + lk * 8];
#pragma unroll
            for (int n = 0; n < 2; n++)
                bf[n] = *(const s16x8*)&Ws[(wc * 32 + n * 16 + lr) * LDT + kk * 32 + lk * 8];
#pragma unroll
            for (int m = 0; m < 4; m++)
#pragma unroll
                for (int n = 0; n < 2; n++)
                    acc[m][n] = __builtin_amdgcn_mfma_f32_16x16x32_bf16(
                        af[m], bf[n], acc[m][n], 0, 0, 0);
        }
    }

    float bv[2];
    if constexpr (!ROWBIAS) {
#pragma unroll
        for (int n = 0; n < 2; n++) bv[n] = bias[n0 + wc * 32 + n * 16 + lr];
    }
#pragma unroll
    for (int m = 0; m < 4; m++) {
#pragma unroll
        for (int j = 0; j < 4; j++) {
            int row = m0 + wr * 64 + m * 16 + lk * 4 + j;
            if (row >= M) continue;
            const float* rb = nullptr;
            if constexpr (ROWBIAS) rb = bias + (size_t)(row / L_) * N;
#pragma unroll
            for (int n = 0; n < 2; n++) {
                int col = n0 + wc * 32 + n * 16 + lr;
                float c = acc[m][n][j];
                if constexpr (ROWBIAS) c += rb[col];
                else                   c += bv[n];
                if constexpr (RELU) c = fmaxf(c, 0.0f);
                if constexpr (RESID) c += bf2f(resid[(size_t)row * N + col]);
                if constexpr (OUTBF) ((u16*)Cout)[(size_t)row * N + col] = f2bf(c);
                else                 ((float*)Cout)[(size_t)row * N + col] = c;
            }
        }
    }
}

// ======================================================================
// LayerNorm: one wave per row; RELU / bf16-out / bf16-in / fused-RoPE.
// ======================================================================
template<int DD, bool RELU, bool OUTBF, bool INBF, bool ROPE>
__global__ __launch_bounds__(256)
void ln_k(const void* __restrict__ xin, const float* __restrict__ s,
          const float* __restrict__ bb, void* __restrict__ out, int M,
          const float* __restrict__ ct = nullptr,
          const float* __restrict__ st = nullptr,
          u16* __restrict__ rout = nullptr)
{
    const int lane = threadIdx.x & 63;
    const int row = (blockIdx.x << 2) + (threadIdx.x >> 6);
    if (row >= M) return;
    constexpr int NV = DD / 64;
    float v[NV];
    if constexpr (INBF) {
        const u16* xr = (const u16*)xin + (size_t)row * DD;
        if constexpr (NV == 8) {
            s16x8 t = *(const s16x8*)(xr + lane * 8);
#pragma unroll
            for (int e = 0; e < 8; e++) v[e] = bf2f((u16)t[e]);
        } else {
            v[0] = bf2f(xr[lane * 2]); v[1] = bf2f(xr[lane * 2 + 1]);
        }
    } else {
        const float* xr = (const float*)xin + (size_t)row * DD;
        if constexpr (NV == 8) {
            *(float4*)(v)     = *(const float4*)(xr + lane * 8);
            *(float4*)(v + 4) = *(const float4*)(xr + lane * 8 + 4);
        } else {
            float2 t = *(const float2*)(xr + lane * 2);
            v[0] = t.x; v[1] = t.y;
        }
    }
    float sum = 0.f, sq = 0.f;
#pragma unroll
    for (int e = 0; e < NV; e++) { sum += v[e]; sq += v[e] * v[e]; }
#pragma unroll
    for (int msk = 1; msk < 64; msk <<= 1) {
        sum += __shfl_xor(sum, msk);
        sq  += __shfl_xor(sq, msk);
    }
    const float mean = sum * (1.0f / DD);
    const float var  = sq * (1.0f / DD) - mean * mean;
    const float rstd = rsqrtf(var + EPS_);
#pragma unroll
    for (int e = 0; e < NV; e++) {
        int d = lane * NV + e;
        float r = (v[e] - mean) * rstd * s[d] + bb[d];
        if constexpr (RELU) r = fmaxf(r, 0.0f);
        v[e] = r;
    }
    if constexpr (OUTBF) {
        u16* orow = (u16*)out + (size_t)row * DD;
        if constexpr (NV == 8) {
            s16x8 o;
#pragma unroll
            for (int e = 0; e < 8; e++) o[e] = (short)f2bf(v[e]);
            *(s16x8*)(orow + lane * 8) = o;
        } else {
            orow[lane * 2] = f2bf(v[0]); orow[lane * 2 + 1] = f2bf(v[1]);
        }
    } else {
        float* orow = (float*)out + (size_t)row * DD;
        if constexpr (NV == 8) {
            *(float4*)(orow + lane * 8)     = *(float4*)(v);
            *(float4*)(orow + lane * 8 + 4) = *(float4*)(v + 4);
        } else {
            float2 t; t.x = v[0]; t.y = v[1];
            *(float2*)(orow + lane * 2) = t;
        }
    }
    if constexpr (ROPE) {
        float pv[8];
#pragma unroll
        for (int e = 0; e < 8; e++) pv[e] = __shfl_xor(v[e], 4);
        const int l = row % L_;
        const int dd0 = (lane & 7) * 8;
        const float sgn = (lane & 4) ? 1.0f : -1.0f;
        float4 c0 = *(const float4*)(ct + l * DH_ + dd0);
        float4 c1 = *(const float4*)(ct + l * DH_ + dd0 + 4);
        float4 s0 = *(const float4*)(st + l * DH_ + dd0);
        float4 s1 = *(const float4*)(st + l * DH_ + dd0 + 4);
        float cc[8] = {c0.x,c0.y,c0.z,c0.w,c1.x,c1.y,c1.z,c1.w};
        float ss[8] = {s0.x,s0.y,s0.z,s0.w,s1.x,s1.y,s1.z,s1.w};
        s16x8 ro;
#pragma unroll
        for (int e = 0; e < 8; e++)
            ro[e] = (short)f2bf(v[e] * cc[e] + sgn * pv[e] * ss[e]);
        *(s16x8*)(rout + (size_t)row * DD + lane * 8) = ro;
    }
}

// ======================================================================
// MFMA flash attention, swapped-operand (S^T = K Q^T), exp2 softmax,
// XCD-aware block swizzle: the 16 q-tile blocks of one (b,h) map to one
// XCD so its 256KB K/V stays L2-resident (grid 2048 % 8 == 0, bijective).
// ======================================================================
__global__ __launch_bounds__(256)
void attn_k(const u16* __restrict__ qk, const u16* __restrict__ v,
            const float* __restrict__ mask, u16* __restrict__ o)
{
    constexpr int LDA = 68;
    __shared__ u16 Kt[64 * LDA];
    __shared__ u16 Vt[64 * LDA];
    const int obid = ((blockIdx.x & 7) << 8) | (blockIdx.x >> 3);
    const int bh = obid >> 4, qt = obid & 15;
    const int b = bh >> 3, h = bh & 7;
    const int tid = threadIdx.x;
    const int lane = tid & 63, w = tid >> 6;
    const int lr = lane & 15, lg = lane >> 4;
    const size_t basebl = (size_t)b * L_;

    const int qrow = qt * 64 + w * 16 + lr;
    const int qc = qrow < L_ ? qrow : L_ - 1;
    s16x8 bq[2];
#pragma unroll
    for (int kk = 0; kk < 2; kk++)
        bq[kk] = *(const s16x8*)(qk + (basebl + qc) * 1024 + h * DH_ + kk * 32 + lg * 8);

    f32x4 oacc[4];            // O^T: col q=lr, rows d = 16*n2 + 4*lg + j
#pragma unroll
    for (int n = 0; n < 4; n++) oacc[n] = (f32x4)0.0f;
    float m_run = -1e30f, l_run = 0.f;

    const int st_key = tid >> 3;          // 0..31 (+32 for u=1)
    const int st_d8 = (tid & 7) << 3;
    const int src0 = lr + ((lane & 16) << 1);   // lr + 32*(lg&1)
    const int src1 = src0 + 16;
    const bool ahi = (lg >> 1) != 0;

    for (int kt = 0; kt < 16; kt++) {
        __syncthreads();          // all waves done reading prev Kt/Vt
#pragma unroll
        for (int u = 0; u < 2; u++) {
            int key = st_key + u * 32;
            int gk = kt * 64 + key; if (gk >= L_) gk = L_ - 1;
            s16x8 kv = *(const s16x8*)(qk + (basebl + gk) * 1024 + 512 + h * DH_ + st_d8);
            s16x8 vv = *(const s16x8*)(v  + (basebl + gk) * D_ + h * DH_ + st_d8);
            *(s16x8*)&Kt[key * LDA + st_d8] = kv;
#pragma unroll
            for (int e = 0; e < 8; e++) Vt[(st_d8 + e) * LDA + key] = (u16)vv[e];
        }
        __syncthreads();

        int gkey = kt * 64 + lane;
        bool vb = (gkey < L_) && (mask[basebl + gkey] > 0.0f);
        u64 vm = __ballot(vb);

        f32x4 sacc[4];
#pragma unroll
        for (int n = 0; n < 4; n++) {
            sacc[n] = (f32x4)0.0f;
#pragma unroll
            for (int kk = 0; kk < 2; kk++) {
                s16x8 ak = *(const s16x8*)&Kt[(n * 16 + lr) * LDA + kk * 32 + lg * 8];
                sacc[n] = __builtin_amdgcn_mfma_f32_16x16x32_bf16(ak, bq[kk], sacc[n], 0, 0, 0);
            }
        }

        float p[4][4];
        float tm = -1e30f;
#pragma unroll
        for (int n = 0; n < 4; n++)
#pragma unroll
            for (int j = 0; j < 4; j++) {
                int kl = 16 * n + 4 * lg + j;
                float s = ((vm >> kl) & 1ull) ? sacc[n][j] : -1e30f;
                p[n][j] = s;
                tm = fmaxf(tm, s);
            }
        tm = fmaxf(tm, __shfl_xor(tm, 16));
        tm = fmaxf(tm, __shfl_xor(tm, 32));
        float nm = fmaxf(m_run, tm);
        float corr = exp2f(m_run - nm);
        m_run = nm;
        float ts = 0.f;
#pragma unroll
        for (int n = 0; n < 4; n++)
#pragma unroll
            for (int j = 0; j < 4; j++) {
                p[n][j] = exp2f(p[n][j] - nm);
                ts += p[n][j];
            }
        ts += __shfl_xor(ts, 16);
        ts += __shfl_xor(ts, 32);
        l_run = l_run * corr + ts;
#pragma unroll
        for (int n = 0; n < 4; n++) oacc[n] *= corr;

        u32 pk[4][2];
#pragma unroll
        for (int n = 0; n < 4; n++) {
            pk[n][0] = pack2bf(p[n][0], p[n][1]);
            pk[n][1] = pack2bf(p[n][2], p[n][3]);
        }
        u32 r0[4][2], r1[4][2];
#pragma unroll
        for (int n = 0; n < 4; n++)
#pragma unroll
            for (int i = 0; i < 2; i++) {
                r0[n][i] = (u32)__shfl((int)pk[n][i], src0);
                r1[n][i] = (u32)__shfl((int)pk[n][i], src1);
            }
#pragma unroll
        for (int kk = 0; kk < 2; kk++) {
            u32x4 bw;
            bw[0] = ahi ? r0[2 * kk + 1][0] : r0[2 * kk][0];
            bw[1] = ahi ? r0[2 * kk + 1][1] : r0[2 * kk][1];
            bw[2] = ahi ? r1[2 * kk + 1][0] : r1[2 * kk][0];
            bw[3] = ahi ? r1[2 * kk + 1][1] : r1[2 * kk][1];
            s16x8 bp = __builtin_bit_cast(s16x8, bw);
#pragma unroll
            for (int n2 = 0; n2 < 4; n2++) {
                s16x8 av = *(const s16x8*)&Vt[(n2 * 16 + lr) * LDA + kk * 32 + lg * 8];
                oacc[n2] = __builtin_amdgcn_mfma_f32_16x16x32_bf16(av, bp, oacc[n2], 0, 0, 0);
            }
        }
    }

    __syncthreads();   // all waves done with Kt/Vt MFMA reads
    u16* Ol = &Kt[w * 16 * LDA];
    float inv = 1.0f / l_run;
#pragma unroll
    for (int n = 0; n < 4; n++)
#pragma unroll
        for (int j = 0; j < 4; j++)
            Ol[lr * LDA + 16 * n + 4 * lg + j] = f2bf(oacc[n][j] * inv);
    int orow = lane >> 2, oc = (lane & 3) * 16;
    int qg = qt * 64 + w * 16 + orow;
    if (qg < L_) {
        s16x8 o0 = *(const s16x8*)&Ol[orow * LDA + oc];
        s16x8 o1 = *(const s16x8*)&Ol[orow * LDA + oc + 8];
        *(s16x8*)(o + (basebl + qg) * D_ + h * DH_ + oc) = o0;
        *(s16x8*)(o + (basebl + qg) * D_ + h * DH_ + oc + 8) = o1;
    }
}

// ======================================================================
// masked mean pool, two-stage (X bf16).
// ======================================================================
__global__ __launch_bounds__(512)
void pool1_k(const u16* __restrict__ x, const float* __restrict__ mask,
             float* __restrict__ pp, float* __restrict__ mp)
{
    const int b = blockIdx.x, sp = blockIdx.y;
    const int d = threadIdx.x;
    const int l0 = sp * 64;
    float acc = 0.f;
    for (int l = l0; l < l0 + 64 && l < L_; l++)
        acc += bf2f(x[((size_t)b * L_ + l) * D_ + d]) * mask[b * L_ + l];
    pp[((size_t)b * 16 + sp) * D_ + d] = acc;
    if (d == 0) {
        float ms = 0.f;
        for (int l = l0; l < l0 + 64 && l < L_; l++) ms += mask[b * L_ + l];
        mp[b * 16 + sp] = ms;
    }
}

__global__ __launch_bounds__(512)
void pool2_k(const float* __restrict__ pp, const float* __restrict__ mp,
             float* __restrict__ g)
{
    const int b = blockIdx.x;
    const int d = threadIdx.x;
    float acc = 0.f, ms = 0.f;
#pragma unroll
    for (int sp = 0; sp < 16; sp++) {
        acc += pp[((size_t)b * 16 + sp) * D_ + d];
        ms += mp[b * 16 + sp];
    }
    g[b * D_ + d] = acc / ms;
}

// ======================================================================
// gpart[b][j] = h1_b[j] + dot(gctx[b], h1_w[j, 512:1024])  (fp32)
// ======================================================================
__global__ __launch_bounds__(256)
void gpart_k(const float* __restrict__ g, const float* __restrict__ h1w,
             const float* __restrict__ h1b, float* __restrict__ gp)
{
    const int lane = threadIdx.x & 63;
    const int gid = (blockIdx.x << 2) + (threadIdx.x >> 6);
    const int b = gid >> 7, j = gid & 127;
    const float* wr = h1w + (size_t)j * (2 * D_) + D_;
    const float* gr = g + b * D_;
    float4 a0 = *(const float4*)(gr + lane * 8);
    float4 a1 = *(const float4*)(gr + lane * 8 + 4);
    float4 w0 = *(const float4*)(wr + lane * 8);
    float4 w1v = *(const float4*)(wr + lane * 8 + 4);
    float acc = a0.x * w0.x + a0.y * w0.y + a0.z * w0.z + a0.w * w0.w
              + a1.x * w1v.x + a1.y * w1v.y + a1.z * w1v.z + a1.w * w1v.w;
#pragma unroll
    for (int msk = 1; msk < 64; msk <<= 1) acc += __shfl_xor(acc, msk);
    if (lane == 0) gp[b * 128 + j] = acc + h1b[j];
}

// ======================================================================
// logits[m] = h2_b + dot(h[m,0:128], h2_w)
// ======================================================================
__global__ __launch_bounds__(256)
void logits_k(const float* __restrict__ h, const float* __restrict__ w,
              const float* __restrict__ bsc, float* __restrict__ out, int M)
{
    const int lane = threadIdx.x & 63;
    const int row = (blockIdx.x << 2) + (threadIdx.x >> 6);
    if (row >= M) return;
    float2 hv = *(const float2*)(h + (size_t)row * 128 + lane * 2);
    float2 wv = *(const float2*)(w + lane * 2);
    float acc = hv.x * wv.x + hv.y * wv.y;
#pragma unroll
    for (int msk = 1; msk < 64; msk <<= 1) acc += __shfl_xor(acc, msk);
    if (lane == 0) out[row] = acc + bsc[0];
}

// ======================================================================
// host orchestration
// ======================================================================
extern "C" void kernel_launch(void* const* d_in, const int* in_sizes, int n_in,
                              void* d_out, int out_size, void* d_ws, size_t ws_size,
                              hipStream_t stream)
{
    const float* emb       = (const float*)d_in[0];
    const float* mask      = (const float*)d_in[1];
    const float* proj_w    = (const float*)d_in[3];
    const float* proj_b    = (const float*)d_in[4];
    const float* proj_ln_s = (const float*)d_in[5];
    const float* proj_ln_b = (const float*)d_in[6];
    const float* ln1_s     = (const float*)d_in[7];
    const float* ln1_b     = (const float*)d_in[8];
    const float* in_w      = (const float*)d_in[9];
    const float* in_b      = (const float*)d_in[10];
    const float* out_w     = (const float*)d_in[11];
    const float* out_b     = (const float*)d_in[12];
    const float* ln2_s     = (const float*)d_in[13];
    const float* ln2_b     = (const float*)d_in[14];
    const float* w1        = (const float*)d_in[15];
    const float* b1        = (const float*)d_in[16];
    const float* w2        = (const float*)d_in[17];
    const float* b2        = (const float*)d_in[18];
    const float* h1_w      = (const float*)d_in[19];
    const float* h1_b      = (const float*)d_in[20];
    const float* hln_s     = (const float*)d_in[21];
    const float* hln_b     = (const float*)d_in[22];
    const float* h2_w      = (const float*)d_in[23];
    const float* h2_b      = (const float*)d_in[24];
    float* out = (float*)d_out;

    // Workspace map (S = BL*D floats):
    //   [0,0.5S)   X bf16 residual stream [BL,512]
    //   [S,2S)     Rf fp32 (proj-out, head Hb) / QKB bf16 [BL,1024] (disjoint)
    //   [2S,2.5S)  VB bf16
    //   [2.5S,3S)  NbB bf16
    //   [3S,5S)    FFb16 bf16 [BL,2048]; aliases embB, RopeB, RB (disjoint)
    //   [5S,...)   bf16 weights, CT/ST/GC/GP/Pp/Mp/QBS
    float* ws = (float*)d_ws;
    const size_t S = (size_t)BL_ * D_;
    u16* X = (u16*)ws;                    // bf16 residual
    float* Rf = ws + S;
    u16* QKB   = (u16*)(ws + S);
    u16* VB    = (u16*)(ws + 2 * S);
    u16* NbB   = (u16*)(ws + 2 * S) + S;
    u16* FFb16 = (u16*)(ws + 3 * S);
    u16* RopeB = FFb16;
    u16* embB  = FFb16;
    u16* RB    = (u16*)(ws + 4 * S);
    u16* projwB = (u16*)(ws + 5 * S);
    u16* iwB  = projwB + 512 * 1280;
    u16* owB  = iwB + (size_t)NL_ * 3 * D_ * D_;
    u16* w1B  = owB + (size_t)NL_ * D_ * D_;
    u16* w2B  = w1B + (size_t)NL_ * FF_ * D_;
    u16* h1wB = w2B + (size_t)NL_ * D_ * FF_;
    float* CT = ws + 5 * S + 6651904;
    float* ST = CT + L_ * DH_;
    float* GC = ST + L_ * DH_;
    float* GP = GC + B_ * D_;
    float* Pp = GP + B_ * 128;            // [B*16, 512] partials
    float* Mp = Pp + (size_t)B_ * 16 * D_;
    float* QBS = Mp + B_ * 16;            // [NL,1024] scaled q/k bias
    float* Hb = Rf;

    const int MT = 128;
    const dim3 blk(256);
    const dim3 gblk(512);
    const int lnGrid = (BL_ + 3) / 4;

    cast_k<<<(BL_ * E_ / 8 + 255) / 256, blk, 0, stream>>>(emb, embB, BL_ * E_ / 8);
    cast_k<<<(512 * 1280 / 8 + 255) / 256, blk, 0, stream>>>(proj_w, projwB, 512 * 1280 / 8);
    castq_k<<<(NL_ * 3 * D_ * D_ / 8 + 255) / 256, blk, 0, stream>>>(in_w, iwB, NL_ * 3 * D_ * D_ / 8);
    qbias_k<<<(NL_ * 1024 + 255) / 256, blk, 0, stream>>>(in_b, QBS);
    cast_k<<<(NL_ * D_ * D_ / 8 + 255) / 256, blk, 0, stream>>>(out_w, owB, NL_ * D_ * D_ / 8);
    cast_k<<<(NL_ * FF_ * D_ / 8 + 255) / 256, blk, 0, stream>>>(w1, w1B, NL_ * FF_ * D_ / 8);
    cast_k<<<(NL_ * D_ * FF_ / 8 + 255) / 256, blk, 0, stream>>>(w2, w2B, NL_ * D_ * FF_ / 8);
    h1cast_k<<<(128 * 512 / 8 + 255) / 256, blk, 0, stream>>>(h1_w, h1wB);
    tables_k<<<(L_ * DH_ + 255) / 256, blk, 0, stream>>>(CT, ST);

    mgemm_k<false,false,false,false><<<MT * (D_ / 128), gblk, 0, stream>>>(
        embB, projwB, proj_b, nullptr, Rf, BL_, D_, E_);
    ln_k<D_,false,true,false,false><<<lnGrid, blk, 0, stream>>>(Rf, proj_ln_s, proj_ln_b, X, BL_);

    for (int i = 0; i < NL_; i++) {
        const u16* iw = iwB + (size_t)i * 3 * D_ * D_;
        const float* ib = in_b + (size_t)i * 3 * D_;
        // fused ln1 + rope: writes NbB (LN out) and RopeB (roped LN out)
        ln_k<D_,false,true,true,true><<<lnGrid, blk, 0, stream>>>(
            X, ln1_s + i * D_, ln1_b + i * D_, NbB, BL_, CT, ST, RopeB);
        mgemm_k<false,false,true,false><<<MT * 4, gblk, 0, stream>>>(
            NbB, iw + 2 * D_ * D_, ib + 2 * D_, nullptr, VB, BL_, D_, D_);
        // fused q+k projection (wq pre-scaled by QSC_, bias = QBS[i])
        mgemm_k<false,false,true,false><<<MT * 8, gblk, 0, stream>>>(
            RopeB, iw, QBS + (size_t)i * 1024, nullptr, QKB, BL_, 1024, D_);
        attn_k<<<B_ * H_ * 16, blk, 0, stream>>>(QKB, VB, mask, RB);
        mgemm_k<false,true,true,false><<<MT * 4, gblk, 0, stream>>>(
            RB, owB + (size_t)i * D_ * D_, out_b + i * D_, X, X, BL_, D_, D_);
        ln_k<D_,false,true,true,false><<<lnGrid, blk, 0, stream>>>(
            X, ln2_s + i * D_, ln2_b + i * D_, NbB, BL_);
        mgemm_k<true,false,true,false><<<MT * 16, gblk, 0, stream>>>(
            NbB, w1B + (size_t)i * FF_ * D_, b1 + i * FF_, nullptr, FFb16, BL_, FF_, D_);
        mgemm_k<false,true,true,false><<<MT * 4, gblk, 0, stream>>>(
            FFb16, w2B + (size_t)i * D_ * FF_, b2 + i * D_, X, X, BL_, D_, FF_);
    }

    pool1_k<<<dim3(B_, 16), dim3(512), 0, stream>>>(X, mask, Pp, Mp);
    pool2_k<<<B_, dim3(512), 0, stream>>>(Pp, Mp, GC);
    gpart_k<<<(B_ * 128) / 4, blk, 0, stream>>>(GC, h1_w, h1_b, GP);
    mgemm_k<false,false,false,true><<<MT * 1, gblk, 0, stream>>>(
        X, h1wB, GP, nullptr, Hb, BL_, 128, D_);
    ln_k<128,true,false,false,false><<<lnGrid, blk, 0, stream>>>(Hb, hln_s, hln_b, Hb, BL_);
    logits_k<<<lnGrid, blk, 0, stream>>>(Hb, h2_w, h2_b, out, BL_);
}

// Round 14
// 1322.376 us; speedup vs baseline: 1.1349x; 1.0490x over previous
//
#include <hip/hip_runtime.h>
#include <cstdint>
#include <cstddef>

// ---------------- problem constants ----------------
#define B_   16
#define L_   1022
#define E_   1280
#define D_   512
#define H_   8
#define FF_  2048
#define NL_  4
#define DH_  64
#define BL_  (B_*L_)      // 16352
#define EPS_ 1e-5f
#define QSC_ 0.18033688011112042f   // 0.125 * log2(e)

typedef unsigned short u16;
typedef unsigned int   u32;
typedef unsigned long long u64;
typedef float f32x4 __attribute__((ext_vector_type(4)));
typedef short s16x8 __attribute__((ext_vector_type(8)));
typedef u32 u32x4 __attribute__((ext_vector_type(4)));

__device__ __forceinline__ u16 f2bf(float f) {
    u32 u = __builtin_bit_cast(u32, f);
    u += 0x7fffu + ((u >> 16) & 1u);
    return (u16)(u >> 16);
}
__device__ __forceinline__ float bf2f(u16 u) {
    return __builtin_bit_cast(float, (u32)u << 16);
}
// hardware packed f32x2 -> bf16x2 (lo=a, hi=b); no builtin on gfx950
__device__ __forceinline__ u32 cvtpk(float a, float b) {
    u32 r;
    asm("v_cvt_pk_bf16_f32 %0, %1, %2" : "=v"(r) : "v"(a), "v"(b));
    return r;
}

// ======================================================================
// fp32 -> bf16 cast, 8 elems/thread
// ======================================================================
__global__ __launch_bounds__(256)
void cast_k(const float* __restrict__ src, u16* __restrict__ dst, int n8) {
    int t = blockIdx.x * 256 + threadIdx.x;
    if (t >= n8) return;
    const float* s = src + (size_t)t * 8;
    float4 a = *(const float4*)(s);
    float4 b = *(const float4*)(s + 4);
    s16x8 o;
    o[0] = (short)f2bf(a.x); o[1] = (short)f2bf(a.y);
    o[2] = (short)f2bf(a.z); o[3] = (short)f2bf(a.w);
    o[4] = (short)f2bf(b.x); o[5] = (short)f2bf(b.y);
    o[6] = (short)f2bf(b.z); o[7] = (short)f2bf(b.w);
    *(s16x8*)(dst + (size_t)t * 8) = o;
}

// in_w cast with wq rows (row%1536 < 512) pre-scaled by QSC_
__global__ __launch_bounds__(256)
void castq_k(const float* __restrict__ src, u16* __restrict__ dst, int n8) {
    int t = blockIdx.x * 256 + threadIdx.x;
    if (t >= n8) return;
    int row = t >> 6;                  // 512 cols / 8 per chunk
    float sc = (row % 1536) < 512 ? QSC_ : 1.0f;
    const float* s = src + (size_t)t * 8;
    float4 a = *(const float4*)(s);
    float4 b = *(const float4*)(s + 4);
    s16x8 o;
    o[0] = (short)f2bf(a.x * sc); o[1] = (short)f2bf(a.y * sc);
    o[2] = (short)f2bf(a.z * sc); o[3] = (short)f2bf(a.w * sc);
    o[4] = (short)f2bf(b.x * sc); o[5] = (short)f2bf(b.y * sc);
    o[6] = (short)f2bf(b.z * sc); o[7] = (short)f2bf(b.w * sc);
    *(s16x8*)(dst + (size_t)t * 8) = o;
}

// scaled q/k bias: qbs[i][j] = in_b[i*1536+j] * (j<512?QSC:1)
__global__ __launch_bounds__(256)
void qbias_k(const float* __restrict__ ib, float* __restrict__ qbs) {
    int t = blockIdx.x * 256 + threadIdx.x;
    if (t >= NL_ * 1024) return;
    int i = t >> 10, j = t & 1023;
    float sc = j < 512 ? QSC_ : 1.0f;
    qbs[t] = ib[i * 1536 + j] * sc;
}

// h1_w left half [128, 0:512] (row stride 1024) -> packed bf16 [128,512]
__global__ __launch_bounds__(256)
void h1cast_k(const float* __restrict__ src, u16* __restrict__ dst) {
    int t = blockIdx.x * 256 + threadIdx.x;
    if (t >= 128 * 512 / 8) return;
    int row = t >> 6, c8 = (t & 63) << 3;
    const float* s = src + (size_t)row * 1024 + c8;
    float4 a = *(const float4*)(s);
    float4 b = *(const float4*)(s + 4);
    s16x8 o;
    o[0] = (short)f2bf(a.x); o[1] = (short)f2bf(a.y);
    o[2] = (short)f2bf(a.z); o[3] = (short)f2bf(a.w);
    o[4] = (short)f2bf(b.x); o[5] = (short)f2bf(b.y);
    o[6] = (short)f2bf(b.z); o[7] = (short)f2bf(b.w);
    *(s16x8*)(dst + (size_t)row * 512 + c8) = o;
}

// ======================================================================
// RoPE cos/sin tables
// ======================================================================
__global__ void tables_k(float* __restrict__ ct, float* __restrict__ st) {
    int idx = blockIdx.x * blockDim.x + threadIdx.x;
    if (idx >= L_ * DH_) return;
    int l = idx / DH_;
    int d = idx % DH_;
    int j = d & 31;
    float invf = powf(10000.0f, -(float)(2 * j) / (float)DH_);
    float ang = (float)l * invf;
    ct[idx] = cosf(ang);
    st[idx] = sinf(ang);
}

// ======================================================================
// bf16 MFMA GEMM (reg-staged, pipelined, XCD-swizzled):
// C = act(A@W^T+b)(+res). 128x128 tile, BK=64, 512 threads / 8 waves.
// XCD swizzle: consecutive obids (sharing the A-panel) land on ONE XCD
// L2 (grid always divisible by 8), cutting A-panel HBM refetch up to 8x.
// ======================================================================
template<bool RELU, bool RESID, bool OUTBF, bool ROWBIAS>
__global__ __launch_bounds__(512)
void mgemm_k(const u16* __restrict__ A, const u16* __restrict__ W,
             const float* __restrict__ bias, const u16* __restrict__ resid,
             void* __restrict__ Cout, int M, int N, int K)
{
    constexpr int LDT = 72;               // padded LDS row stride (bf16)
    __shared__ u16 As[128 * LDT];
    __shared__ u16 Ws[128 * LDT];
    const int nt = N >> 7;
    const int bid = (int)blockIdx.x;
    const int obid = (bid & 7) * ((int)gridDim.x >> 3) + (bid >> 3);
    const int bx = obid % nt;
    const int by = obid / nt;
    const int m0 = by << 7, n0 = bx << 7;
    const int tid = threadIdx.x;
    const int lane = tid & 63, wid = tid >> 6;
    const int wr = wid >> 2, wc = wid & 3;     // 2x4 wave grid
    const int lr = lane & 15, lk = lane >> 4;

    f32x4 acc[4][2];
#pragma unroll
    for (int m = 0; m < 4; m++)
#pragma unroll
        for (int n = 0; n < 2; n++) acc[m][n] = (f32x4)0.0f;

    s16x8 va[2], vw[2];
    auto load_tiles = [&](int k0) {
#pragma unroll
        for (int u = 0; u < 2; u++) {
            int ch = tid + (u << 9);          // 16B chunk id, 0..1023
            int r = ch >> 3, c8 = (ch & 7) << 3;
            int ar = m0 + r; if (ar >= M) ar = M - 1;
            va[u] = *(const s16x8*)(A + (size_t)ar * K + k0 + c8);
            vw[u] = *(const s16x8*)(W + (size_t)(n0 + r) * K + k0 + c8);
        }
    };

    load_tiles(0);
    for (int k0 = 0; k0 < K; k0 += 64) {
        __syncthreads();   // previous iteration's LDS reads complete
#pragma unroll
        for (int u = 0; u < 2; u++) {
            int ch = tid + (u << 9);
            int r = ch >> 3, c8 = (ch & 7) << 3;
            *(s16x8*)&As[r * LDT + c8] = va[u];
            *(s16x8*)&Ws[r * LDT + c8] = vw[u];
        }
        __syncthreads();   // tiles staged
        if (k0 + 64 < K) load_tiles(k0 + 64);   // prefetch under MFMA
#pragma unroll
        for (int kk = 0; kk < 2; kk++) {
            s16x8 af[4], bf[2];
#pragma unroll
            for (int m = 0; m < 4; m++)
                af[m] = *(const s16x8*)&As[(wr * 64 + m * 16 + lr) * LDT + kk * 32 + lk * 8];
#pragma unroll
            for (int n = 0; n < 2; n++)
                bf[n] = *(const s16x8*)&Ws[(wc * 32 + n * 16 + lr) * LDT + kk * 32 + lk * 8];
#pragma unroll
            for (int m = 0; m < 4; m++)
#pragma unroll
                for (int n = 0; n < 2; n++)
                    acc[m][n] = __builtin_amdgcn_mfma_f32_16x16x32_bf16(
                        af[m], bf[n], acc[m][n], 0, 0, 0);
        }
    }

    float bv[2];
    if constexpr (!ROWBIAS) {
#pragma unroll
        for (int n = 0; n < 2; n++) bv[n] = bias[n0 + wc * 32 + n * 16 + lr];
    }
#pragma unroll
    for (int m = 0; m < 4; m++) {
#pragma unroll
        for (int j = 0; j < 4; j++) {
            int row = m0 + wr * 64 + m * 16 + lk * 4 + j;
            if (row >= M) continue;
            const float* rb = nullptr;
            if constexpr (ROWBIAS) rb = bias + (size_t)(row / L_) * N;
#pragma unroll
            for (int n = 0; n < 2; n++) {
                int col = n0 + wc * 32 + n * 16 + lr;
                float c = acc[m][n][j];
                if constexpr (ROWBIAS) c += rb[col];
                else                   c += bv[n];
                if constexpr (RELU) c = fmaxf(c, 0.0f);
                if constexpr (RESID) c += bf2f(resid[(size_t)row * N + col]);
                if constexpr (OUTBF) ((u16*)Cout)[(size_t)row * N + col] = f2bf(c);
                else                 ((float*)Cout)[(size_t)row * N + col] = c;
            }
        }
    }
}

// ======================================================================
// LayerNorm: one wave per row; RELU / bf16-out / bf16-in / fused-RoPE.
// ======================================================================
template<int DD, bool RELU, bool OUTBF, bool INBF, bool ROPE>
__global__ __launch_bounds__(256)
void ln_k(const void* __restrict__ xin, const float* __restrict__ s,
          const float* __restrict__ bb, void* __restrict__ out, int M,
          const float* __restrict__ ct = nullptr,
          const float* __restrict__ st = nullptr,
          u16* __restrict__ rout = nullptr)
{
    const int lane = threadIdx.x & 63;
    const int row = (blockIdx.x << 2) + (threadIdx.x >> 6);
    if (row >= M) return;
    constexpr int NV = DD / 64;
    float v[NV];
    if constexpr (INBF) {
        const u16* xr = (const u16*)xin + (size_t)row * DD;
        if constexpr (NV == 8) {
            s16x8 t = *(const s16x8*)(xr + lane * 8);
#pragma unroll
            for (int e = 0; e < 8; e++) v[e] = bf2f((u16)t[e]);
        } else {
            v[0] = bf2f(xr[lane * 2]); v[1] = bf2f(xr[lane * 2 + 1]);
        }
    } else {
        const float* xr = (const float*)xin + (size_t)row * DD;
        if constexpr (NV == 8) {
            *(float4*)(v)     = *(const float4*)(xr + lane * 8);
            *(float4*)(v + 4) = *(const float4*)(xr + lane * 8 + 4);
        } else {
            float2 t = *(const float2*)(xr + lane * 2);
            v[0] = t.x; v[1] = t.y;
        }
    }
    float sum = 0.f, sq = 0.f;
#pragma unroll
    for (int e = 0; e < NV; e++) { sum += v[e]; sq += v[e] * v[e]; }
#pragma unroll
    for (int msk = 1; msk < 64; msk <<= 1) {
        sum += __shfl_xor(sum, msk);
        sq  += __shfl_xor(sq, msk);
    }
    const float mean = sum * (1.0f / DD);
    const float var  = sq * (1.0f / DD) - mean * mean;
    const float rstd = rsqrtf(var + EPS_);
#pragma unroll
    for (int e = 0; e < NV; e++) {
        int d = lane * NV + e;
        float r = (v[e] - mean) * rstd * s[d] + bb[d];
        if constexpr (RELU) r = fmaxf(r, 0.0f);
        v[e] = r;
    }
    if constexpr (OUTBF) {
        u16* orow = (u16*)out + (size_t)row * DD;
        if constexpr (NV == 8) {
            s16x8 o;
#pragma unroll
            for (int e = 0; e < 8; e++) o[e] = (short)f2bf(v[e]);
            *(s16x8*)(orow + lane * 8) = o;
        } else {
            orow[lane * 2] = f2bf(v[0]); orow[lane * 2 + 1] = f2bf(v[1]);
        }
    } else {
        float* orow = (float*)out + (size_t)row * DD;
        if constexpr (NV == 8) {
            *(float4*)(orow + lane * 8)     = *(float4*)(v);
            *(float4*)(orow + lane * 8 + 4) = *(float4*)(v + 4);
        } else {
            float2 t; t.x = v[0]; t.y = v[1];
            *(float2*)(orow + lane * 2) = t;
        }
    }
    if constexpr (ROPE) {
        float pv[8];
#pragma unroll
        for (int e = 0; e < 8; e++) pv[e] = __shfl_xor(v[e], 4);
        const int l = row % L_;
        const int dd0 = (lane & 7) * 8;
        const float sgn = (lane & 4) ? 1.0f : -1.0f;
        float4 c0 = *(const float4*)(ct + l * DH_ + dd0);
        float4 c1 = *(const float4*)(ct + l * DH_ + dd0 + 4);
        float4 s0 = *(const float4*)(st + l * DH_ + dd0);
        float4 s1 = *(const float4*)(st + l * DH_ + dd0 + 4);
        float cc[8] = {c0.x,c0.y,c0.z,c0.w,c1.x,c1.y,c1.z,c1.w};
        float ss[8] = {s0.x,s0.y,s0.z,s0.w,s1.x,s1.y,s1.z,s1.w};
        s16x8 ro;
#pragma unroll
        for (int e = 0; e < 8; e++)
            ro[e] = (short)f2bf(v[e] * cc[e] + sgn * pv[e] * ss[e]);
        *(s16x8*)(rout + (size_t)row * DD + lane * 8) = ro;
    }
}

// ======================================================================
// MFMA flash attention, swapped-operand (S^T = K Q^T), exp2 softmax,
// XCD swizzle, hardware cvt_pk for P/O bf16 packing.
// ======================================================================
__global__ __launch_bounds__(256)
void attn_k(const u16* __restrict__ qk, const u16* __restrict__ v,
            const float* __restrict__ mask, u16* __restrict__ o)
{
    constexpr int LDA = 68;
    __shared__ u16 Kt[64 * LDA];
    __shared__ u16 Vt[64 * LDA];
    const int obid = ((blockIdx.x & 7) << 8) | (blockIdx.x >> 3);
    const int bh = obid >> 4, qt = obid & 15;
    const int b = bh >> 3, h = bh & 7;
    const int tid = threadIdx.x;
    const int lane = tid & 63, w = tid >> 6;
    const int lr = lane & 15, lg = lane >> 4;
    const size_t basebl = (size_t)b * L_;

    const int qrow = qt * 64 + w * 16 + lr;
    const int qc = qrow < L_ ? qrow : L_ - 1;
    s16x8 bq[2];
#pragma unroll
    for (int kk = 0; kk < 2; kk++)
        bq[kk] = *(const s16x8*)(qk + (basebl + qc) * 1024 + h * DH_ + kk * 32 + lg * 8);

    f32x4 oacc[4];            // O^T: col q=lr, rows d = 16*n2 + 4*lg + j
#pragma unroll
    for (int n = 0; n < 4; n++) oacc[n] = (f32x4)0.0f;
    float m_run = -1e30f, l_run = 0.f;

    const int st_key = tid >> 3;          // 0..31 (+32 for u=1)
    const int st_d8 = (tid & 7) << 3;
    const int src0 = lr + ((lane & 16) << 1);   // lr + 32*(lg&1)
    const int src1 = src0 + 16;
    const bool ahi = (lg >> 1) != 0;

    for (int kt = 0; kt < 16; kt++) {
        __syncthreads();          // all waves done reading prev Kt/Vt
#pragma unroll
        for (int u = 0; u < 2; u++) {
            int key = st_key + u * 32;
            int gk = kt * 64 + key; if (gk >= L_) gk = L_ - 1;
            s16x8 kv = *(const s16x8*)(qk + (basebl + gk) * 1024 + 512 + h * DH_ + st_d8);
            s16x8 vv = *(const s16x8*)(v  + (basebl + gk) * D_ + h * DH_ + st_d8);
            *(s16x8*)&Kt[key * LDA + st_d8] = kv;
#pragma unroll
            for (int e = 0; e < 8; e++) Vt[(st_d8 + e) * LDA + key] = (u16)vv[e];
        }
        __syncthreads();

        int gkey = kt * 64 + lane;
        bool vb = (gkey < L_) && (mask[basebl + gkey] > 0.0f);
        u64 vm = __ballot(vb);

        f32x4 sacc[4];
#pragma unroll
        for (int n = 0; n < 4; n++) {
            sacc[n] = (f32x4)0.0f;
#pragma unroll
            for (int kk = 0; kk < 2; kk++) {
                s16x8 ak = *(const s16x8*)&Kt[(n * 16 + lr) * LDA + kk * 32 + lg * 8];
                sacc[n] = __builtin_amdgcn_mfma_f32_16x16x32_bf16(ak, bq[kk], sacc[n], 0, 0, 0);
            }
        }

        float p[4][4];
        float tm = -1e30f;
#pragma unroll
        for (int n = 0; n < 4; n++)
#pragma unroll
            for (int j = 0; j < 4; j++) {
                int kl = 16 * n + 4 * lg + j;
                float s = ((vm >> kl) & 1ull) ? sacc[n][j] : -1e30f;
                p[n][j] = s;
                tm = fmaxf(tm, s);
            }
        tm = fmaxf(tm, __shfl_xor(tm, 16));
        tm = fmaxf(tm, __shfl_xor(tm, 32));
        float nm = fmaxf(m_run, tm);
        float corr = exp2f(m_run - nm);
        m_run = nm;
        float ts = 0.f;
#pragma unroll
        for (int n = 0; n < 4; n++)
#pragma unroll
            for (int j = 0; j < 4; j++) {
                p[n][j] = exp2f(p[n][j] - nm);
                ts += p[n][j];
            }
        ts += __shfl_xor(ts, 16);
        ts += __shfl_xor(ts, 32);
        l_run = l_run * corr + ts;
#pragma unroll
        for (int n = 0; n < 4; n++) oacc[n] *= corr;

        // pack P via hardware cvt_pk; redistribute to PV B-frag layout
        u32 pk[4][2];
#pragma unroll
        for (int n = 0; n < 4; n++) {
            pk[n][0] = cvtpk(p[n][0], p[n][1]);
            pk[n][1] = cvtpk(p[n][2], p[n][3]);
        }
        u32 r0[4][2], r1[4][2];
#pragma unroll
        for (int n = 0; n < 4; n++)
#pragma unroll
            for (int i = 0; i < 2; i++) {
                r0[n][i] = (u32)__shfl((int)pk[n][i], src0);
                r1[n][i] = (u32)__shfl((int)pk[n][i], src1);
            }
#pragma unroll
        for (int kk = 0; kk < 2; kk++) {
            u32x4 bw;
            bw[0] = ahi ? r0[2 * kk + 1][0] : r0[2 * kk][0];
            bw[1] = ahi ? r0[2 * kk + 1][1] : r0[2 * kk][1];
            bw[2] = ahi ? r1[2 * kk + 1][0] : r1[2 * kk][0];
            bw[3] = ahi ? r1[2 * kk + 1][1] : r1[2 * kk][1];
            s16x8 bp = __builtin_bit_cast(s16x8, bw);
#pragma unroll
            for (int n2 = 0; n2 < 4; n2++) {
                s16x8 av = *(const s16x8*)&Vt[(n2 * 16 + lr) * LDA + kk * 32 + lg * 8];
                oacc[n2] = __builtin_amdgcn_mfma_f32_16x16x32_bf16(av, bp, oacc[n2], 0, 0, 0);
            }
        }
    }

    __syncthreads();   // all waves done with Kt/Vt MFMA reads
    u16* Ol = &Kt[w * 16 * LDA];
    float inv = 1.0f / l_run;
#pragma unroll
    for (int n = 0; n < 4; n++) {
        u32 w0 = cvtpk(oacc[n][0] * inv, oacc[n][1] * inv);
        u32 w1 = cvtpk(oacc[n][2] * inv, oacc[n][3] * inv);
        u32* dst = (u32*)&Ol[lr * LDA + 16 * n + 4 * lg];
        dst[0] = w0; dst[1] = w1;
    }
    int orow = lane >> 2, oc = (lane & 3) * 16;
    int qg = qt * 64 + w * 16 + orow;
    if (qg < L_) {
        s16x8 o0 = *(const s16x8*)&Ol[orow * LDA + oc];
        s16x8 o1 = *(const s16x8*)&Ol[orow * LDA + oc + 8];
        *(s16x8*)(o + (basebl + qg) * D_ + h * DH_ + oc) = o0;
        *(s16x8*)(o + (basebl + qg) * D_ + h * DH_ + oc + 8) = o1;
    }
}

// ======================================================================
// masked mean pool, two-stage (X bf16).
// ======================================================================
__global__ __launch_bounds__(512)
void pool1_k(const u16* __restrict__ x, const float* __restrict__ mask,
             float* __restrict__ pp, float* __restrict__ mp)
{
    const int b = blockIdx.x, sp = blockIdx.y;
    const int d = threadIdx.x;
    const int l0 = sp * 64;
    float acc = 0.f;
    for (int l = l0; l < l0 + 64 && l < L_; l++)
        acc += bf2f(x[((size_t)b * L_ + l) * D_ + d]) * mask[b * L_ + l];
    pp[((size_t)b * 16 + sp) * D_ + d] = acc;
    if (d == 0) {
        float ms = 0.f;
        for (int l = l0; l < l0 + 64 && l < L_; l++) ms += mask[b * L_ + l];
        mp[b * 16 + sp] = ms;
    }
}

__global__ __launch_bounds__(512)
void pool2_k(const float* __restrict__ pp, const float* __restrict__ mp,
             float* __restrict__ g)
{
    const int b = blockIdx.x;
    const int d = threadIdx.x;
    float acc = 0.f, ms = 0.f;
#pragma unroll
    for (int sp = 0; sp < 16; sp++) {
        acc += pp[((size_t)b * 16 + sp) * D_ + d];
        ms += mp[b * 16 + sp];
    }
    g[b * D_ + d] = acc / ms;
}

// ======================================================================
// gpart[b][j] = h1_b[j] + dot(gctx[b], h1_w[j, 512:1024])  (fp32)
// ======================================================================
__global__ __launch_bounds__(256)
void gpart_k(const float* __restrict__ g, const float* __restrict__ h1w,
             const float* __restrict__ h1b, float* __restrict__ gp)
{
    const int lane = threadIdx.x & 63;
    const int gid = (blockIdx.x << 2) + (threadIdx.x >> 6);
    const int b = gid >> 7, j = gid & 127;
    const float* wr = h1w + (size_t)j * (2 * D_) + D_;
    const float* gr = g + b * D_;
    float4 a0 = *(const float4*)(gr + lane * 8);
    float4 a1 = *(const float4*)(gr + lane * 8 + 4);
    float4 w0 = *(const float4*)(wr + lane * 8);
    float4 w1v = *(const float4*)(wr + lane * 8 + 4);
    float acc = a0.x * w0.x + a0.y * w0.y + a0.z * w0.z + a0.w * w0.w
              + a1.x * w1v.x + a1.y * w1v.y + a1.z * w1v.z + a1.w * w1v.w;
#pragma unroll
    for (int msk = 1; msk < 64; msk <<= 1) acc += __shfl_xor(acc, msk);
    if (lane == 0) gp[b * 128 + j] = acc + h1b[j];
}

// ======================================================================
// logits[m] = h2_b + dot(h[m,0:128], h2_w)
// ======================================================================
__global__ __launch_bounds__(256)
void logits_k(const float* __restrict__ h, const float* __restrict__ w,
              const float* __restrict__ bsc, float* __restrict__ out, int M)
{
    const int lane = threadIdx.x & 63;
    const int row = (blockIdx.x << 2) + (threadIdx.x >> 6);
    if (row >= M) return;
    float2 hv = *(const float2*)(h + (size_t)row * 128 + lane * 2);
    float2 wv = *(const float2*)(w + lane * 2);
    float acc = hv.x * wv.x + hv.y * wv.y;
#pragma unroll
    for (int msk = 1; msk < 64; msk <<= 1) acc += __shfl_xor(acc, msk);
    if (lane == 0) out[row] = acc + bsc[0];
}

// ======================================================================
// host orchestration
// ======================================================================
extern "C" void kernel_launch(void* const* d_in, const int* in_sizes, int n_in,
                              void* d_out, int out_size, void* d_ws, size_t ws_size,
                              hipStream_t stream)
{
    const float* emb       = (const float*)d_in[0];
    const float* mask      = (const float*)d_in[1];
    const float* proj_w    = (const float*)d_in[3];
    const float* proj_b    = (const float*)d_in[4];
    const float* proj_ln_s = (const float*)d_in[5];
    const float* proj_ln_b = (const float*)d_in[6];
    const float* ln1_s     = (const float*)d_in[7];
    const float* ln1_b     = (const float*)d_in[8];
    const float* in_w      = (const float*)d_in[9];
    const float* in_b      = (const float*)d_in[10];
    const float* out_w     = (const float*)d_in[11];
    const float* out_b     = (const float*)d_in[12];
    const float* ln2_s     = (const float*)d_in[13];
    const float* ln2_b     = (const float*)d_in[14];
    const float* w1        = (const float*)d_in[15];
    const float* b1        = (const float*)d_in[16];
    const float* w2        = (const float*)d_in[17];
    const float* b2        = (const float*)d_in[18];
    const float* h1_w      = (const float*)d_in[19];
    const float* h1_b      = (const float*)d_in[20];
    const float* hln_s     = (const float*)d_in[21];
    const float* hln_b     = (const float*)d_in[22];
    const float* h2_w      = (const float*)d_in[23];
    const float* h2_b      = (const float*)d_in[24];
    float* out = (float*)d_out;

    // Workspace map (S = BL*D floats):
    //   [0,0.5S)   X bf16 residual stream [BL,512]
    //   [S,2S)     Rf fp32 (proj-out, head Hb) / QKB bf16 [BL,1024] (disjoint)
    //   [2S,2.5S)  VB bf16
    //   [2.5S,3S)  NbB bf16
    //   [3S,5S)    FFb16 bf16 [BL,2048]; aliases embB, RopeB, RB (disjoint)
    //   [5S,...)   bf16 weights, CT/ST/GC/GP/Pp/Mp/QBS
    float* ws = (float*)d_ws;
    const size_t S = (size_t)BL_ * D_;
    u16* X = (u16*)ws;                    // bf16 residual
    float* Rf = ws + S;
    u16* QKB   = (u16*)(ws + S);
    u16* VB    = (u16*)(ws + 2 * S);
    u16* NbB   = (u16*)(ws + 2 * S) + S;
    u16* FFb16 = (u16*)(ws + 3 * S);
    u16* RopeB = FFb16;
    u16* embB  = FFb16;
    u16* RB    = (u16*)(ws + 4 * S);
    u16* projwB = (u16*)(ws + 5 * S);
    u16* iwB  = projwB + 512 * 1280;
    u16* owB  = iwB + (size_t)NL_ * 3 * D_ * D_;
    u16* w1B  = owB + (size_t)NL_ * D_ * D_;
    u16* w2B  = w1B + (size_t)NL_ * FF_ * D_;
    u16* h1wB = w2B + (size_t)NL_ * D_ * FF_;
    float* CT = ws + 5 * S + 6651904;
    float* ST = CT + L_ * DH_;
    float* GC = ST + L_ * DH_;
    float* GP = GC + B_ * D_;
    float* Pp = GP + B_ * 128;            // [B*16, 512] partials
    float* Mp = Pp + (size_t)B_ * 16 * D_;
    float* QBS = Mp + B_ * 16;            // [NL,1024] scaled q/k bias
    float* Hb = Rf;

    const int MT = 128;
    const dim3 blk(256);
    const dim3 gblk(512);
    const int lnGrid = (BL_ + 3) / 4;

    cast_k<<<(BL_ * E_ / 8 + 255) / 256, blk, 0, stream>>>(emb, embB, BL_ * E_ / 8);
    cast_k<<<(512 * 1280 / 8 + 255) / 256, blk, 0, stream>>>(proj_w, projwB, 512 * 1280 / 8);
    castq_k<<<(NL_ * 3 * D_ * D_ / 8 + 255) / 256, blk, 0, stream>>>(in_w, iwB, NL_ * 3 * D_ * D_ / 8);
    qbias_k<<<(NL_ * 1024 + 255) / 256, blk, 0, stream>>>(in_b, QBS);
    cast_k<<<(NL_ * D_ * D_ / 8 + 255) / 256, blk, 0, stream>>>(out_w, owB, NL_ * D_ * D_ / 8);
    cast_k<<<(NL_ * FF_ * D_ / 8 + 255) / 256, blk, 0, stream>>>(w1, w1B, NL_ * FF_ * D_ / 8);
    cast_k<<<(NL_ * D_ * FF_ / 8 + 255) / 256, blk, 0, stream>>>(w2, w2B, NL_ * D_ * FF_ / 8);
    h1cast_k<<<(128 * 512 / 8 + 255) / 256, blk, 0, stream>>>(h1_w, h1wB);
    tables_k<<<(L_ * DH_ + 255) / 256, blk, 0, stream>>>(CT, ST);

    mgemm_k<false,false,false,false><<<MT * (D_ / 128), gblk, 0, stream>>>(
        embB, projwB, proj_b, nullptr, Rf, BL_, D_, E_);
    ln_k<D_,false,true,false,false><<<lnGrid, blk, 0, stream>>>(Rf, proj_ln_s, proj_ln_b, X, BL_);

    for (int i = 0; i < NL_; i++) {
        const u16* iw = iwB + (size_t)i * 3 * D_ * D_;
        const float* ib = in_b + (size_t)i * 3 * D_;
        // fused ln1 + rope: writes NbB (LN out) and RopeB (roped LN out)
        ln_k<D_,false,true,true,true><<<lnGrid, blk, 0, stream>>>(
            X, ln1_s + i * D_, ln1_b + i * D_, NbB, BL_, CT, ST, RopeB);
        mgemm_k<false,false,true,false><<<MT * 4, gblk, 0, stream>>>(
            NbB, iw + 2 * D_ * D_, ib + 2 * D_, nullptr, VB, BL_, D_, D_);
        // fused q+k projection (wq pre-scaled by QSC_, bias = QBS[i])
        mgemm_k<false,false,true,false><<<MT * 8, gblk, 0, stream>>>(
            RopeB, iw, QBS + (size_t)i * 1024, nullptr, QKB, BL_, 1024, D_);
        attn_k<<<B_ * H_ * 16, blk, 0, stream>>>(QKB, VB, mask, RB);
        mgemm_k<false,true,true,false><<<MT * 4, gblk, 0, stream>>>(
            RB, owB + (size_t)i * D_ * D_, out_b + i * D_, X, X, BL_, D_, D_);
        ln_k<D_,false,true,true,false><<<lnGrid, blk, 0, stream>>>(
            X, ln2_s + i * D_, ln2_b + i * D_, NbB, BL_);
        mgemm_k<true,false,true,false><<<MT * 16, gblk, 0, stream>>>(
            NbB, w1B + (size_t)i * FF_ * D_, b1 + i * FF_, nullptr, FFb16, BL_, FF_, D_);
        mgemm_k<false,true,true,false><<<MT * 4, gblk, 0, stream>>>(
            FFb16, w2B + (size_t)i * D_ * FF_, b2 + i * D_, X, X, BL_, D_, FF_);
    }

    pool1_k<<<dim3(B_, 16), dim3(512), 0, stream>>>(X, mask, Pp, Mp);
    pool2_k<<<B_, dim3(512), 0, stream>>>(Pp, Mp, GC);
    gpart_k<<<(B_ * 128) / 4, blk, 0, stream>>>(GC, h1_w, h1_b, GP);
    mgemm_k<false,false,false,true><<<MT * 1, gblk, 0, stream>>>(
        X, h1wB, GP, nullptr, Hb, BL_, 128, D_);
    ln_k<128,true,false,false,false><<<lnGrid, blk, 0, stream>>>(Hb, hln_s, hln_b, Hb, BL_);
    logits_k<<<lnGrid, blk, 0, stream>>>(Hb, h2_w, h2_b, out, BL_);
}